// Round 10
// baseline (199.230 us; speedup 1.0000x reference)
//
#include <hip/hip_runtime.h>
#include <hip/hip_bf16.h>
#include <stdint.h>

// Problem constants
// B=128 STREAM=512 IN_CH=4 EXTRA=5 GROUPS=2 DEPTH=3 STEP=16 LENGTH=32 RNN=256 OUT=10
// C=10 SIG_C=1110 W=31 F=2220, padded K = 2240, GEMM M = 31*128 = 3968, N = 768
// gi layout (f16, COALESCED): chunk u of thread gtid at step (t,bb):
//   f16 offset = ((t*8+bb)*6 + u)*2048 + gtid*4,  u = gs*2+gtc in [0,6)
// gi VALUES pre-scaled for exp2-based gate math:
//   r,z chunks: -log2e*(gemm + b_ih + b_hh);  n chunks: 2*log2e*(gemm + b_ih)
// GEMM: 64x64 tiles, 744 blocks, 6-buffer 5-deep global_load_lds pipeline
//   (round-9 config, frozen: -3.2us real).
// GRU (round 10): 16 waves (1024 thr, 4 waves/SIMD). Each wave owns 16 gate
//   cols x 3 gates. Unspillable budget: 64 AGPR (r a[0:15], z a[16:31] fp8;
//   n a[32:63] f16) + ~36 asm VGPRs = 100 < 128 -> compiles at 4 waves/EU
//   (round-1 crash was 112 AGPR + all-f16 = 180 unspillable). Per-wave MFMA
//   and gate VALU halve; TLP doubles; same MFMA chain per 16-col tile ->
//   bitwise-identical output.

typedef _Float16 f16;
typedef f16  f16x2 __attribute__((ext_vector_type(2)));
typedef f16  f16x4 __attribute__((ext_vector_type(4)));
typedef f16  f16x8 __attribute__((ext_vector_type(8)));
typedef float f32x2 __attribute__((ext_vector_type(2)));
typedef float f32x4 __attribute__((ext_vector_type(4)));

#define ASYNC16(gp, lp) __builtin_amdgcn_global_load_lds( \
    (const __attribute__((address_space(1))) void*)(gp),  \
    (__attribute__((address_space(3))) void*)(lp), 16, 0, 0)

#define BAR_LDS() do { asm volatile("s_waitcnt lgkmcnt(0)" ::: "memory"); \
                       __builtin_amdgcn_s_barrier();                      \
                       asm volatile("" ::: "memory"); } while (0)

__device__ __forceinline__ float fexp2(float x) {
    float r; asm("v_exp_f32 %0, %1" : "=v"(r) : "v"(x)); return r;
}
__device__ __forceinline__ float frcp(float x) {
    float r; asm("v_rcp_f32 %0, %1" : "=v"(r) : "v"(x)); return r;
}

// ---------------------------------------------------------------- K0: prep
// blocks [0,840):    W_ih f32 -> f16 (pad 2220->2240), 8 elems/thread
// blocks [840,936):  W_hh f32 -> f16 (all) + fp8*16 (r,z rows), 8 elems/thread
// blocks [936,2920): signature chains, 4/block; LDS-staged coalesced row store
__global__ __launch_bounds__(256) void prep_kernel(const float* __restrict__ x,
                                                   const float* __restrict__ W_aug,
                                                   const float* __restrict__ Wih,
                                                   const float* __restrict__ Whh,
                                                   f16* __restrict__ sig16,
                                                   f16* __restrict__ wih16,
                                                   f16* __restrict__ whh16,
                                                   uint8_t* __restrict__ whh8) {
    __shared__ float dxs[4][31][10];
    __shared__ f16 srow[4][1112];                  // per-chain staging (1110 + pad)
    const int tid = threadIdx.x;
    if (blockIdx.x < 840) {
        int c = blockIdx.x * 256 + tid;          // chunk 0..215039
        int r = c / 280, kc = (c - r * 280) * 8;
        const float* src = Wih + (size_t)r * 2220 + kc;
        f16x8 o;
        if (kc + 8 <= 2220) {
            float4 v0 = *(const float4*)(src);
            float4 v1 = *(const float4*)(src + 4);
            o[0]=(f16)v0.x; o[1]=(f16)v0.y; o[2]=(f16)v0.z; o[3]=(f16)v0.w;
            o[4]=(f16)v1.x; o[5]=(f16)v1.y; o[6]=(f16)v1.z; o[7]=(f16)v1.w;
        } else {
#pragma unroll
            for (int j = 0; j < 8; j++)
                o[j] = (f16)((kc + j < 2220) ? src[j] : 0.0f);
        }
        *(f16x8*)(wih16 + (size_t)r * 2240 + kc) = o;
        return;
    }
    if (blockIdx.x < 936) {
        int c2 = ((int)blockIdx.x - 840) * 256 + tid;    // 0..24575
        int j8 = c2 * 8;
        float w[8];
        {
            float4 v0 = *(const float4*)(Whh + j8);
            float4 v1 = *(const float4*)(Whh + j8 + 4);
            w[0]=v0.x; w[1]=v0.y; w[2]=v0.z; w[3]=v0.w;
            w[4]=v1.x; w[5]=v1.y; w[6]=v1.z; w[7]=v1.w;
        }
        f16x8 o;
#pragma unroll
        for (int j = 0; j < 8; j++) o[j] = (f16)w[j];
        *(f16x8*)(whh16 + j8) = o;
        if (j8 < 131072) {                       // r,z gate rows -> fp8 e4m3 (x16)
            uint32_t p01 = (uint32_t)__builtin_amdgcn_cvt_pk_fp8_f32(w[0]*16.f, w[1]*16.f, 0, false) & 0xffffu;
            uint32_t p23 = (uint32_t)__builtin_amdgcn_cvt_pk_fp8_f32(w[2]*16.f, w[3]*16.f, 0, false) & 0xffffu;
            uint32_t p45 = (uint32_t)__builtin_amdgcn_cvt_pk_fp8_f32(w[4]*16.f, w[5]*16.f, 0, false) & 0xffffu;
            uint32_t p67 = (uint32_t)__builtin_amdgcn_cvt_pk_fp8_f32(w[6]*16.f, w[7]*16.f, 0, false) & 0xffffu;
            uint2 st = make_uint2(p01 | (p23 << 16), p45 | (p67 << 16));
            *(uint2*)(whh8 + j8) = st;
        }
        return;
    }
    // ---- signature chains (block-uniform branch; __syncthreads safe)
    const int sub = tid >> 6, t64 = tid & 63;
    const int cid = ((int)blockIdx.x - 936) * 4 + sub;   // 0..7935
    const int w = cid % 31;
    const int bg = cid / 31;
    const int b = bg >> 1, g = bg & 1;
    if (t64 < 31) {
        int s = w * 16 + t64;
        const float4 x0 = *(const float4*)(x + ((size_t)b * 512 + s) * 4);
        const float4 x1 = *(const float4*)(x + ((size_t)b * 512 + s + 1) * 4);
        float d0 = x1.x - x0.x, d1 = x1.y - x0.y, d2 = x1.z - x0.z, d3 = x1.w - x0.w;
        dxs[sub][t64][0] = d0; dxs[sub][t64][1] = d1;
        dxs[sub][t64][2] = d2; dxs[sub][t64][3] = d3;
        dxs[sub][t64][4] = 1.0f / 511.0f;
#pragma unroll
        for (int e = 0; e < 5; e++) {
            const float* wa = W_aug + (g * 5 + e) * 4;
            dxs[sub][t64][5 + e] = d0 * wa[0] + d1 * wa[1] + d2 * wa[2] + d3 * wa[3];
        }
    }
    __syncthreads();
    size_t base = ((size_t)(w * 128 + b)) * 2240 + (size_t)g * 1110;
    if (t64 < 50) {
        int p0 = 2 * t64, p1 = p0 + 1;
        int i0 = p0 / 10, j0 = p0 % 10, j1 = j0 + 1;   // p0 even -> j1 <= 9
        const float* dz  = &dxs[sub][0][0];
        const float* pI  = dz + i0;
        const float* pJ0 = dz + j0;
        const float* pJ1 = dz + j1;
        float s3a[10], s3b[10];
#pragma unroll
        for (int k = 0; k < 10; k++) { s3a[k] = 0.f; s3b[k] = 0.f; }
        float s2a = 0.f, s2b = 0.f, s1 = 0.f;
        for (int l = 0; l < 31; l++) {
            const float* row = dz + l * 10;
            float di  = pI[l * 10];
            float dj0 = pJ0[l * 10];
            float dj1 = pJ1[l * 10];
            float t0 = s1 + di * (1.0f / 3.0f);
            float a0 = s2a + t0 * (0.5f * dj0);
            float a1 = s2b + t0 * (0.5f * dj1);
#pragma unroll
            for (int k = 0; k < 10; k++) {
                float dk = row[k];
                s3a[k] += a0 * dk;
                s3b[k] += a1 * dk;
            }
            float u = s1 + 0.5f * di;
            s2a += u * dj0;
            s2b += u * dj1;
            s1 += di;
        }
        *(f16x2*)&srow[sub][10 + p0] = (f16x2){(f16)s2a, (f16)s2b};
#pragma unroll
        for (int k = 0; k < 5; k++)
            *(f16x2*)&srow[sub][110 + p0 * 10 + 2 * k] =
                (f16x2){(f16)s3a[2 * k], (f16)s3a[2 * k + 1]};
#pragma unroll
        for (int k = 0; k < 5; k++)
            *(f16x2*)&srow[sub][110 + p1 * 10 + 2 * k] =
                (f16x2){(f16)s3b[2 * k], (f16)s3b[2 * k + 1]};
    } else if (t64 < 60) {
        int c = t64 - 50;
        const float* pc = &dxs[sub][0][0] + c;
        float s = 0.f;
        for (int l = 0; l < 31; l++) s += pc[l * 10];
        srow[sub][c] = (f16)s;
    }
    __syncthreads();
    for (int j = t64; j < 555; j += 64)
        *(f16x2*)(sig16 + base + 2 * j) = *(const f16x2*)&srow[sub][2 * j];
    if (g == 1 && t64 < 10)
        *(f16x2*)(sig16 + ((size_t)(w * 128 + b)) * 2240 + 2220 + 2 * t64) =
            (f16x2){(f16)0.0f, (f16)0.0f};
}

// ---------------------------------------------------------------- K2: gi = sig @ W_ih.T + biases (f16, coalesced GRU layout)
// 64x64 tile, 744 blocks, 4 waves, 6-buffer 5-deep pipeline (round-9, frozen).
__global__ __launch_bounds__(256) void gemm_kernel(const f16* __restrict__ A,     // 3968 x 2240
                                                   const f16* __restrict__ Bw,    // 768 x 2240 f16
                                                   const float* __restrict__ bias,
                                                   const float* __restrict__ bhh,
                                                   f16* __restrict__ Cgi) {
    const int lin = blockIdx.x;          // 744 = 62 mb x 12 nc
    const int nc = lin % 12;
    const int mb = lin / 12;             // 0..61
    const int t = mb >> 1, half = mb & 1;
    __shared__ __align__(16) f16 As[6][64 * 32];    // 24 KB
    __shared__ __align__(16) f16 Bs[6][64 * 32];    // 24 KB (48 total -> 3 blocks/CU)
    const int tid = threadIdx.x, lane = tid & 63, wid = tid >> 6;   // wid 0..3
    const int l16 = lane & 15, quad = lane >> 4;
    const int lrow = lane >> 2, lk = lane & 3;
    const int Nbase = nc * 64;
    const f16* gaA = A  + (size_t)(mb * 64 + wid * 16 + lrow) * 2240 + lk * 8;
    const f16* gbB = Bw + (size_t)(Nbase + wid * 16 + lrow) * 2240 + lk * 8;

#define GISSUE(KT, BUF) do { \
        int _k0 = (KT) * 32; \
        ASYNC16(gaA + _k0, &As[BUF][(wid * 16) * 32]); \
        ASYNC16(gbB + _k0, &Bs[BUF][(wid * 16) * 32]); } while (0)

#define GCOMPUTE(BUF) do { \
        f16x8 af, bf[4]; \
        af = *(const f16x8*)&As[BUF][(wid * 16 + l16) * 32 + quad * 8]; \
        _Pragma("unroll") \
        for (int nt = 0; nt < 4; nt++) \
            bf[nt] = *(const f16x8*)&Bs[BUF][(nt * 16 + l16) * 32 + quad * 8]; \
        _Pragma("unroll") \
        for (int nt = 0; nt < 4; nt++) \
            acc[nt] = __builtin_amdgcn_mfma_f32_16x16x32_f16(af, bf[nt], acc[nt], 0, 0, 0); } while (0)

    f32x4 acc[4];
#pragma unroll
    for (int nt = 0; nt < 4; nt++) acc[nt] = (f32x4){0.f, 0.f, 0.f, 0.f};

    GISSUE(0, 0); GISSUE(1, 1); GISSUE(2, 2); GISSUE(3, 3); GISSUE(4, 4);
    for (int kt = 0; kt < 65; kt++) {
        asm volatile("s_waitcnt vmcnt(8) lgkmcnt(0)\n\ts_barrier" ::: "memory");
        GISSUE(kt + 5, (kt + 5) % 6);
        GCOMPUTE(kt % 6);
    }
    asm volatile("s_waitcnt vmcnt(8) lgkmcnt(0)\n\ts_barrier" ::: "memory");
    GCOMPUTE(5);
    asm volatile("s_waitcnt vmcnt(6) lgkmcnt(0)\n\ts_barrier" ::: "memory");
    GCOMPUTE(0);
    asm volatile("s_waitcnt vmcnt(4) lgkmcnt(0)\n\ts_barrier" ::: "memory");
    GCOMPUTE(1);
    asm volatile("s_waitcnt vmcnt(2) lgkmcnt(0)\n\ts_barrier" ::: "memory");
    GCOMPUTE(2);
    asm volatile("s_waitcnt vmcnt(0) lgkmcnt(0)\n\ts_barrier" ::: "memory");
    GCOMPUTE(3);

    const float NEG_LOG2E = -1.4426950408889634f;
    const float TWO_LOG2E =  2.8853900817779268f;
    const int bbv = half * 4 + wid;
#pragma unroll
    for (int nt = 0; nt < 4; nt++) {
        int col = Nbase + nt * 16 + l16;
        float bvv = bias[col] + (col < 512 ? bhh[col] : 0.0f);
        float scl = (col < 512) ? NEG_LOG2E : TWO_LOG2E;
        int gs = col >> 8, hcc = col & 255;
        int gw = hcc >> 5, gtc = (hcc >> 4) & 1, gl = hcc & 15;
        int u = gs * 2 + gtc;
        int gtid = gw * 64 + quad * 16 + gl;
        size_t off = ((size_t)((t * 8 + bbv) * 6 + u)) * 2048 + (size_t)gtid * 4;
        f16x4 st;
#pragma unroll
        for (int rr = 0; rr < 4; rr++) st[rr] = (f16)((acc[nt][rr] + bvv) * scl);
        *(f16x4*)(Cgi + off) = st;
    }
#undef GISSUE
#undef GCOMPUTE
}

// ---------------------------------------------------------------- K3: GRU scan (16 waves)
// Unspillable: 64 AGPR weights + ~36 asm VGPRs = 100 < 128 (4 waves/EU).
#define ACLOB64 \
  "a0","a1","a2","a3","a4","a5","a6","a7","a8","a9","a10","a11","a12","a13","a14","a15", \
  "a16","a17","a18","a19","a20","a21","a22","a23","a24","a25","a26","a27","a28","a29","a30","a31", \
  "a32","a33","a34","a35","a36","a37","a38","a39","a40","a41","a42","a43","a44","a45","a46","a47", \
  "a48","a49","a50","a51","a52","a53","a54","a55","a56","a57","a58","a59","a60","a61","a62","a63"

// fp8 weight frag (16 gate cols x 32 k) -> 2 AGPRs.  G: 0=r rows, 1=z rows.
#define LF8(A0,A1, G, KT) do { \
  f32x2 _t = *(const f32x2*)(whh8 + (size_t)((G) * 256 + wid * 16 + l16) * 256 + (KT) * 32 + quad * 8); \
  asm volatile("v_accvgpr_write_b32 a" #A0 ", %0\n\t" \
               "v_accvgpr_write_b32 a" #A1 ", %1" \
               :: "v"(_t[0]), "v"(_t[1]) : "a" #A0, "a" #A1); } while (0)

// f16 n-gate frag (16 cols x 32 k) -> 4 AGPRs.
#define LFN(A0,A1,A2,A3, KT) do { \
  f32x4 _t = *(const f32x4*)(whh16 + (size_t)(512 + wid * 16 + l16) * 256 + (KT) * 32 + quad * 8); \
  asm volatile("v_accvgpr_write_b32 a" #A0 ", %0\n\t" \
               "v_accvgpr_write_b32 a" #A1 ", %1\n\t" \
               "v_accvgpr_write_b32 a" #A2 ", %2\n\t" \
               "v_accvgpr_write_b32 a" #A3 ", %3" \
               :: "v"(_t[0]), "v"(_t[1]), "v"(_t[2]), "v"(_t[3]) \
               : "a" #A0, "a" #A1, "a" #A2, "a" #A3); } while (0)

#define RZGZ(P, F0,F1) \
  "v_mfma_f32_16x16x32_fp8_fp8 %[aR], " P ", a[" F0 "], %[zq]\n\t" \
  "v_mfma_f32_16x16x32_fp8_fp8 %[aZ], " P ", a[" F1 "], %[zq]\n\t"

#define RZG(P, F0,F1) \
  "v_mfma_f32_16x16x32_fp8_fp8 %[aR], " P ", a[" F0 "], %[aR]\n\t" \
  "v_mfma_f32_16x16x32_fp8_fp8 %[aZ], " P ", a[" F1 "], %[aZ]\n\t"

#define NGZ(Q, G0) \
  "v_mfma_f32_16x16x32_f16 %[aN], " Q ", a[" G0 "], %[zq]\n\t"

#define NG(Q, G0) \
  "v_mfma_f32_16x16x32_f16 %[aN], " Q ", a[" G0 "], %[aN]\n\t"

__global__ __launch_bounds__(1024, 4) void gru_kernel(const f16* __restrict__ gi,
                                                      const f16* __restrict__ whh16,
                                                      const uint8_t* __restrict__ whh8,
                                                      const float* __restrict__ b_hh,
                                                      const float* __restrict__ W_out,
                                                      const float* __restrict__ b_out,
                                                      float* __restrict__ out) {
    __shared__ __align__(16) f16 hbufF[2][16 * 280];      // f16 h (n-gate A + head)
    __shared__ __align__(16) uint8_t hbuf8[2][16 * 272];  // fp8 h (rz A)
    const int tid = threadIdx.x, lane = tid & 63, wid = tid >> 6;   // wid 0..15
    const int quad = lane >> 4, l16 = lane & 15;
    const int bb = blockIdx.x;

    for (int i = tid; i < 16 * 280; i += 1024) hbufF[1][i] = (f16)0.0f;
    for (int i = tid; i < 16 * 272; i += 1024) hbuf8[1][i] = 0;

    // r: a[0:15], z: a[16:31] (fp8, 2/frag); n: a[32:63] (f16, 4/frag)
    LF8(0,1,   0,0); LF8(2,3,   0,1); LF8(4,5,   0,2); LF8(6,7,   0,3);
    LF8(8,9,   0,4); LF8(10,11, 0,5); LF8(12,13, 0,6); LF8(14,15, 0,7);
    LF8(16,17, 1,0); LF8(18,19, 1,1); LF8(20,21, 1,2); LF8(22,23, 1,3);
    LF8(24,25, 1,4); LF8(26,27, 1,5); LF8(28,29, 1,6); LF8(30,31, 1,7);
    LFN(32,33,34,35, 0); LFN(36,37,38,39, 1); LFN(40,41,42,43, 2); LFN(44,45,46,47, 3);
    LFN(48,49,50,51, 4); LFN(52,53,54,55, 5); LFN(56,57,58,59, 6); LFN(60,61,62,63, 7);

    const float C2 = 2.8853900817779268f;   // 2*log2e
    const int hcx = wid * 16 + l16;         // owned gate column
    const float bhn = C2 * b_hh[512 + hcx];
    float hm[4];
#pragma unroll
    for (int rr = 0; rr < 4; rr++) hm[rr] = 0.f;

    uint32_t aF0 = (uint32_t)(uintptr_t)(__attribute__((address_space(3))) const void*)
                       (&hbufF[0][l16 * 280 + quad * 8]);
    uint32_t aF1 = (uint32_t)(uintptr_t)(__attribute__((address_space(3))) const void*)
                       (&hbufF[1][l16 * 280 + quad * 8]);
    uint32_t a80 = (uint32_t)(uintptr_t)(__attribute__((address_space(3))) const void*)
                       (&hbuf8[0][l16 * 272 + quad * 8]);
    uint32_t a81 = (uint32_t)(uintptr_t)(__attribute__((address_space(3))) const void*)
                       (&hbuf8[1][l16 * 272 + quad * 8]);

    // coalesced gi: wave owns cols wid*16..+16 -> u-chunk parity wid&1,
    // thread slot (wid>>1)*64 + quad*16 + l16; gate chunks at +gs*4096.
    const size_t lanebase = (size_t)bb * 12288 + (size_t)(wid & 1) * 2048
                          + (size_t)((wid >> 1) * 64 + quad * 16 + l16) * 4;
    f16x4 gcur[3];
#pragma unroll
    for (int gs = 0; gs < 3; gs++)
        gcur[gs] = *(const f16x4*)(gi + lanebase + (size_t)gs * 4096);

    const f32x4 zq = (f32x4){0.f, 0.f, 0.f, 0.f};

    BAR_LDS();

    for (int t = 0; t < 31; t++) {
        const uint32_t a8 = (t & 1) ? a80 : a81;
        const uint32_t aF = (t & 1) ? aF0 : aF1;
        f32x4 aR, aZ, aN;
        f32x2 p0, p1, p2;
        f32x4 q0, q1, q2;
        asm volatile(
            "s_setprio 1\n\t"
            "ds_read_b64  %[p0], %[a8] offset:0\n\t"
            "ds_read_b128 %[q0], %[aF] offset:0\n\t"
            "ds_read_b64  %[p1], %[a8] offset:32\n\t"
            "ds_read_b128 %[q1], %[aF] offset:64\n\t"
            "ds_read_b64  %[p2], %[a8] offset:64\n\t"
            "ds_read_b128 %[q2], %[aF] offset:128\n\t"
            "s_waitcnt lgkmcnt(5)\n\t"
            RZGZ("%[p0]", "0:1", "16:17")
            "ds_read_b64  %[p0], %[a8] offset:96\n\t"
            "s_waitcnt lgkmcnt(5)\n\t"
            NGZ("%[q0]", "32:35")
            "ds_read_b128 %[q0], %[aF] offset:192\n\t"
            "s_waitcnt lgkmcnt(5)\n\t"
            RZG("%[p1]", "2:3", "18:19")
            "ds_read_b64  %[p1], %[a8] offset:128\n\t"
            "s_waitcnt lgkmcnt(5)\n\t"
            NG("%[q1]", "36:39")
            "ds_read_b128 %[q1], %[aF] offset:256\n\t"
            "s_waitcnt lgkmcnt(5)\n\t"
            RZG("%[p2]", "4:5", "20:21")
            "ds_read_b64  %[p2], %[a8] offset:160\n\t"
            "s_waitcnt lgkmcnt(5)\n\t"
            NG("%[q2]", "40:43")
            "ds_read_b128 %[q2], %[aF] offset:320\n\t"
            "s_waitcnt lgkmcnt(5)\n\t"
            RZG("%[p0]", "6:7", "22:23")
            "ds_read_b64  %[p0], %[a8] offset:192\n\t"
            "s_waitcnt lgkmcnt(5)\n\t"
            NG("%[q0]", "44:47")
            "ds_read_b128 %[q0], %[aF] offset:384\n\t"
            "s_waitcnt lgkmcnt(5)\n\t"
            RZG("%[p1]", "8:9", "24:25")
            "ds_read_b64  %[p1], %[a8] offset:224\n\t"
            "s_waitcnt lgkmcnt(5)\n\t"
            NG("%[q1]", "48:51")
            "ds_read_b128 %[q1], %[aF] offset:448\n\t"
            "s_waitcnt lgkmcnt(5)\n\t"
            RZG("%[p2]", "10:11", "26:27")
            "s_waitcnt lgkmcnt(4)\n\t"
            NG("%[q2]", "52:55")
            "s_waitcnt lgkmcnt(3)\n\t"
            RZG("%[p0]", "12:13", "28:29")
            "s_waitcnt lgkmcnt(2)\n\t"
            NG("%[q0]", "56:59")
            "s_waitcnt lgkmcnt(1)\n\t"
            RZG("%[p1]", "14:15", "30:31")
            "s_waitcnt lgkmcnt(0)\n\t"
            NG("%[q1]", "60:63")
            "s_setprio 0\n\t"
            "s_nop 7\n\ts_nop 7"
            : [aR]"=&v"(aR), [aZ]"=&v"(aZ), [aN]"=&v"(aN),
              [p0]"=&v"(p0), [p1]"=&v"(p1), [p2]"=&v"(p2),
              [q0]"=&v"(q0), [q1]"=&v"(q1), [q2]"=&v"(q2)
            : [a8]"v"(a8), [aF]"v"(aF), [zq]"v"(zq)
            : ACLOB64);

        // gate math (exp2 form): aR/aZ rz matmul (x1/16), aN n matmul
        f16* hdF = hbufF[t & 1];
        uint8_t* hd8 = hbuf8[t & 1];
        const float C1N16 = -0.09016844005556021f;   // -log2e/16
#pragma unroll
        for (int rr = 0; rr < 4; rr++) {
            float rg = frcp(1.f + fexp2(fmaf(C1N16, aR[rr], (float)gcur[0][rr])));
            float zg = frcp(1.f + fexp2(fmaf(C1N16, aZ[rr], (float)gcur[1][rr])));
            float t2 = fmaf(rg, fmaf(C2, aN[rr], bhn), (float)gcur[2][rr]);
            float e2 = fexp2(t2);
            float ng = fmaf(-2.f, frcp(e2 + 1.f), 1.f);   // tanh
            float h  = fmaf(zg, hm[rr] - ng, ng);         // (1-z)n + z*h
            hm[rr] = h;
            hdF[(quad * 4 + rr) * 280 + hcx] = (f16)h;
            int pk = __builtin_amdgcn_cvt_pk_fp8_f32(h, h, 0, false);
            hd8[(quad * 4 + rr) * 272 + hcx] = (uint8_t)pk;
        }
        // prefetch gi for t+1 (registers; survives lgkm-only barrier)
        {
            int tn = (t < 30) ? t + 1 : 30;
            const f16* gsrc = gi + (size_t)tn * 98304 + lanebase;
#pragma unroll
            for (int gs = 0; gs < 3; gs++)
                gcur[gs] = *(const f16x4*)(gsrc + (size_t)gs * 4096);
        }
        BAR_LDS();
    }
    // output head: final h in hbufF[0]
    if (tid < 160) {
        int r = tid / 10, oc = tid - r * 10;
        const f16* hfin = hbufF[0];
        float s = b_out[oc];
        for (int k = 0; k < 256; k++) s += (float)hfin[r * 280 + k] * W_out[oc * 256 + k];
        out[(bb * 16 + r) * 10 + oc] = frcp(1.f + __expf(-s));
    }
}

// ---------------------------------------------------------------- launch
extern "C" void kernel_launch(void* const* d_in, const int* in_sizes, int n_in,
                              void* d_out, int out_size, void* d_ws, size_t ws_size,
                              hipStream_t stream) {
    const float* x     = (const float*)d_in[0];
    const float* W_aug = (const float*)d_in[1];
    // d_in[2] = b_aug — cancels in dx, unused
    const float* W_ih  = (const float*)d_in[3];
    const float* W_hh  = (const float*)d_in[4];
    const float* b_ih  = (const float*)d_in[5];
    const float* b_hh  = (const float*)d_in[6];
    const float* W_out = (const float*)d_in[7];
    const float* b_out = (const float*)d_in[8];
    float* out = (float*)d_out;

    char* ws = (char*)d_ws;
    const size_t SIG_BYTES  = (size_t)3968 * 2240 * 2;           // 17,776,640
    const size_t WIH_BYTES  = (size_t)768 * 2240 * 2;            //  3,440,640
    const size_t WHH_BYTES  = (size_t)768 * 256 * 2;             //    393,216
    const size_t WHH8_BYTES = (size_t)512 * 256;                 //    131,072
    const size_t GI_BYTES   = (size_t)31 * 8 * 6 * 512 * 4 * 2;  //  6,094,848
    if (ws_size < SIG_BYTES + WIH_BYTES + WHH_BYTES + WHH8_BYTES + GI_BYTES) return;
    f16* sig16    = (f16*)ws;
    f16* wih16    = (f16*)(ws + SIG_BYTES);
    f16* whh16    = (f16*)(ws + SIG_BYTES + WIH_BYTES);
    uint8_t* whh8 = (uint8_t*)(ws + SIG_BYTES + WIH_BYTES + WHH_BYTES);
    f16* giw      = (f16*)(ws + SIG_BYTES + WIH_BYTES + WHH_BYTES + WHH8_BYTES);

    hipLaunchKernelGGL(prep_kernel, dim3(2920), dim3(256), 0, stream,
                       x, W_aug, W_ih, W_hh, sig16, wih16, whh16, whh8);
    hipLaunchKernelGGL(gemm_kernel, dim3(744), dim3(256), 0, stream,
                       sig16, wih16, b_ih, b_hh, giw);
    hipLaunchKernelGGL(gru_kernel, dim3(8), dim3(1024), 0, stream,
                       giw, whh16, whh8, b_hh, W_out, b_out, out);
}

// Round 11
// 195.392 us; speedup vs baseline: 1.0196x; 1.0196x over previous
//
#include <hip/hip_runtime.h>
#include <hip/hip_bf16.h>
#include <stdint.h>

// Problem constants
// B=128 STREAM=512 IN_CH=4 EXTRA=5 GROUPS=2 DEPTH=3 STEP=16 LENGTH=32 RNN=256 OUT=10
// C=10 SIG_C=1110 W=31 F=2220, padded K = 2240, GEMM M = 31*128 = 3968, N = 768
// gi layout (f16, COALESCED): chunk u of thread gtid at step (t,bb):
//   f16 offset = ((t*8+bb)*6 + u)*2048 + gtid*4,  u = gs*2+gtc in [0,6)
// gi VALUES pre-scaled for exp2-based gate math:
//   r,z chunks: -log2e*(gemm + b_ih + b_hh);  n chunks: 2*log2e*(gemm + b_ih)
// GEMM (round 11): IN-BLOCK SPLIT-K. gemm runs ~1885cy/K-iter vs ~100cy work
//   (95% stall, latency-per-iter bound theory). 512 thr: waves 0-3 accumulate
//   K[0,1120), waves 4-7 K[1120,2240) -> serial K-chain 70 -> 35 iters.
//   Partials combined via 16KB LDS scratch; f32 add; epilogue as round 9.
//   LDS 48KB staging + 16KB scratch = 64KB -> 2 blocks/CU -> 4 waves/SIMD.
//   Traffic unchanged (427MB) -> if L3-BW-bound this is null and that theory
//   wins; if latency-bound, gemm ~halves.
// GRU: round-9 8-wave version RESTORED (round-10 16-wave regressed 66->69.9:
//   step is serial-chain + issue bound, not TLP bound).
// prep: unchanged.

typedef _Float16 f16;
typedef f16  f16x2 __attribute__((ext_vector_type(2)));
typedef f16  f16x4 __attribute__((ext_vector_type(4)));
typedef f16  f16x8 __attribute__((ext_vector_type(8)));
typedef float f32x2 __attribute__((ext_vector_type(2)));
typedef float f32x4 __attribute__((ext_vector_type(4)));

#define ASYNC16(gp, lp) __builtin_amdgcn_global_load_lds( \
    (const __attribute__((address_space(1))) void*)(gp),  \
    (__attribute__((address_space(3))) void*)(lp), 16, 0, 0)

#define BAR_LDS() do { asm volatile("s_waitcnt lgkmcnt(0)" ::: "memory"); \
                       __builtin_amdgcn_s_barrier();                      \
                       asm volatile("" ::: "memory"); } while (0)

__device__ __forceinline__ float fexp2(float x) {
    float r; asm("v_exp_f32 %0, %1" : "=v"(r) : "v"(x)); return r;
}
__device__ __forceinline__ float frcp(float x) {
    float r; asm("v_rcp_f32 %0, %1" : "=v"(r) : "v"(x)); return r;
}

// ---------------------------------------------------------------- K0: prep
// blocks [0,840):    W_ih f32 -> f16 (pad 2220->2240), 8 elems/thread
// blocks [840,936):  W_hh f32 -> f16 (all) + fp8*16 (r,z rows), 8 elems/thread
// blocks [936,2920): signature chains, 4/block; LDS-staged coalesced row store
__global__ __launch_bounds__(256) void prep_kernel(const float* __restrict__ x,
                                                   const float* __restrict__ W_aug,
                                                   const float* __restrict__ Wih,
                                                   const float* __restrict__ Whh,
                                                   f16* __restrict__ sig16,
                                                   f16* __restrict__ wih16,
                                                   f16* __restrict__ whh16,
                                                   uint8_t* __restrict__ whh8) {
    __shared__ float dxs[4][31][10];
    __shared__ f16 srow[4][1112];                  // per-chain staging (1110 + pad)
    const int tid = threadIdx.x;
    if (blockIdx.x < 840) {
        int c = blockIdx.x * 256 + tid;          // chunk 0..215039
        int r = c / 280, kc = (c - r * 280) * 8;
        const float* src = Wih + (size_t)r * 2220 + kc;
        f16x8 o;
        if (kc + 8 <= 2220) {
            float4 v0 = *(const float4*)(src);
            float4 v1 = *(const float4*)(src + 4);
            o[0]=(f16)v0.x; o[1]=(f16)v0.y; o[2]=(f16)v0.z; o[3]=(f16)v0.w;
            o[4]=(f16)v1.x; o[5]=(f16)v1.y; o[6]=(f16)v1.z; o[7]=(f16)v1.w;
        } else {
#pragma unroll
            for (int j = 0; j < 8; j++)
                o[j] = (f16)((kc + j < 2220) ? src[j] : 0.0f);
        }
        *(f16x8*)(wih16 + (size_t)r * 2240 + kc) = o;
        return;
    }
    if (blockIdx.x < 936) {
        int c2 = ((int)blockIdx.x - 840) * 256 + tid;    // 0..24575
        int j8 = c2 * 8;
        float w[8];
        {
            float4 v0 = *(const float4*)(Whh + j8);
            float4 v1 = *(const float4*)(Whh + j8 + 4);
            w[0]=v0.x; w[1]=v0.y; w[2]=v0.z; w[3]=v0.w;
            w[4]=v1.x; w[5]=v1.y; w[6]=v1.z; w[7]=v1.w;
        }
        f16x8 o;
#pragma unroll
        for (int j = 0; j < 8; j++) o[j] = (f16)w[j];
        *(f16x8*)(whh16 + j8) = o;
        if (j8 < 131072) {                       // r,z gate rows -> fp8 e4m3 (x16)
            uint32_t p01 = (uint32_t)__builtin_amdgcn_cvt_pk_fp8_f32(w[0]*16.f, w[1]*16.f, 0, false) & 0xffffu;
            uint32_t p23 = (uint32_t)__builtin_amdgcn_cvt_pk_fp8_f32(w[2]*16.f, w[3]*16.f, 0, false) & 0xffffu;
            uint32_t p45 = (uint32_t)__builtin_amdgcn_cvt_pk_fp8_f32(w[4]*16.f, w[5]*16.f, 0, false) & 0xffffu;
            uint32_t p67 = (uint32_t)__builtin_amdgcn_cvt_pk_fp8_f32(w[6]*16.f, w[7]*16.f, 0, false) & 0xffffu;
            uint2 st = make_uint2(p01 | (p23 << 16), p45 | (p67 << 16));
            *(uint2*)(whh8 + j8) = st;
        }
        return;
    }
    // ---- signature chains (block-uniform branch; __syncthreads safe)
    const int sub = tid >> 6, t64 = tid & 63;
    const int cid = ((int)blockIdx.x - 936) * 4 + sub;   // 0..7935
    const int w = cid % 31;
    const int bg = cid / 31;
    const int b = bg >> 1, g = bg & 1;
    if (t64 < 31) {
        int s = w * 16 + t64;
        const float4 x0 = *(const float4*)(x + ((size_t)b * 512 + s) * 4);
        const float4 x1 = *(const float4*)(x + ((size_t)b * 512 + s + 1) * 4);
        float d0 = x1.x - x0.x, d1 = x1.y - x0.y, d2 = x1.z - x0.z, d3 = x1.w - x0.w;
        dxs[sub][t64][0] = d0; dxs[sub][t64][1] = d1;
        dxs[sub][t64][2] = d2; dxs[sub][t64][3] = d3;
        dxs[sub][t64][4] = 1.0f / 511.0f;
#pragma unroll
        for (int e = 0; e < 5; e++) {
            const float* wa = W_aug + (g * 5 + e) * 4;
            dxs[sub][t64][5 + e] = d0 * wa[0] + d1 * wa[1] + d2 * wa[2] + d3 * wa[3];
        }
    }
    __syncthreads();
    size_t base = ((size_t)(w * 128 + b)) * 2240 + (size_t)g * 1110;
    if (t64 < 50) {
        int p0 = 2 * t64, p1 = p0 + 1;
        int i0 = p0 / 10, j0 = p0 % 10, j1 = j0 + 1;   // p0 even -> j1 <= 9
        const float* dz  = &dxs[sub][0][0];
        const float* pI  = dz + i0;
        const float* pJ0 = dz + j0;
        const float* pJ1 = dz + j1;
        float s3a[10], s3b[10];
#pragma unroll
        for (int k = 0; k < 10; k++) { s3a[k] = 0.f; s3b[k] = 0.f; }
        float s2a = 0.f, s2b = 0.f, s1 = 0.f;
        for (int l = 0; l < 31; l++) {
            const float* row = dz + l * 10;
            float di  = pI[l * 10];
            float dj0 = pJ0[l * 10];
            float dj1 = pJ1[l * 10];
            float t0 = s1 + di * (1.0f / 3.0f);
            float a0 = s2a + t0 * (0.5f * dj0);
            float a1 = s2b + t0 * (0.5f * dj1);
#pragma unroll
            for (int k = 0; k < 10; k++) {
                float dk = row[k];
                s3a[k] += a0 * dk;
                s3b[k] += a1 * dk;
            }
            float u = s1 + 0.5f * di;
            s2a += u * dj0;
            s2b += u * dj1;
            s1 += di;
        }
        *(f16x2*)&srow[sub][10 + p0] = (f16x2){(f16)s2a, (f16)s2b};
#pragma unroll
        for (int k = 0; k < 5; k++)
            *(f16x2*)&srow[sub][110 + p0 * 10 + 2 * k] =
                (f16x2){(f16)s3a[2 * k], (f16)s3a[2 * k + 1]};
#pragma unroll
        for (int k = 0; k < 5; k++)
            *(f16x2*)&srow[sub][110 + p1 * 10 + 2 * k] =
                (f16x2){(f16)s3b[2 * k], (f16)s3b[2 * k + 1]};
    } else if (t64 < 60) {
        int c = t64 - 50;
        const float* pc = &dxs[sub][0][0] + c;
        float s = 0.f;
        for (int l = 0; l < 31; l++) s += pc[l * 10];
        srow[sub][c] = (f16)s;
    }
    __syncthreads();
    for (int j = t64; j < 555; j += 64)
        *(f16x2*)(sig16 + base + 2 * j) = *(const f16x2*)&srow[sub][2 * j];
    if (g == 1 && t64 < 10)
        *(f16x2*)(sig16 + ((size_t)(w * 128 + b)) * 2240 + 2220 + 2 * t64) =
            (f16x2){(f16)0.0f, (f16)0.0f};
}

// ---------------------------------------------------------------- K2: gi = sig @ W_ih.T + biases (f16, coalesced GRU layout)
// 64x64 tile, 744 blocks x 512 thr; in-block split-K (waves 0-3 kh=0, 4-7 kh=1,
// 35 iters each); 3-buffer 2-deep pipeline per half; LDS-scratch combine.
__global__ __launch_bounds__(512) void gemm_kernel(const f16* __restrict__ A,     // 3968 x 2240
                                                   const f16* __restrict__ Bw,    // 768 x 2240 f16
                                                   const float* __restrict__ bias,
                                                   const float* __restrict__ bhh,
                                                   f16* __restrict__ Cgi) {
    const int lin = blockIdx.x;          // 744 = 62 mb x 12 nc
    const int nc = lin % 12;
    const int mb = lin / 12;             // 0..61
    const int t = mb >> 1, half = mb & 1;
    __shared__ __align__(16) f16 As[2][3][64 * 32];   // 24 KB
    __shared__ __align__(16) f16 Bs[2][3][64 * 32];   // 24 KB
    __shared__ __align__(16) float sc[4][16 * 64];    // 16 KB (total 64 KB -> 2 blocks/CU)
    const int tid = threadIdx.x, lane = tid & 63, wid = tid >> 6;   // wid 0..7
    const int kh = wid >> 2, w4 = wid & 3;            // K-half, wave-in-half
    const int l16 = lane & 15, quad = lane >> 4;
    const int lrow = lane >> 2, lk = lane & 3;
    const int Nbase = nc * 64;
    // per-wave staging: A rows [w4*16,+16), B rows [w4*16,+16) of this K-half
    const f16* gaA = A  + (size_t)(mb * 64 + w4 * 16 + lrow) * 2240 + kh * 1120 + lk * 8;
    const f16* gbB = Bw + (size_t)(Nbase + w4 * 16 + lrow) * 2240 + kh * 1120 + lk * 8;

#define GISSUE(KT, BUF) do { \
        int _k0 = (KT) * 32; \
        ASYNC16(gaA + _k0, &As[kh][BUF][(w4 * 16) * 32]); \
        ASYNC16(gbB + _k0, &Bs[kh][BUF][(w4 * 16) * 32]); } while (0)

#define GCOMPUTE(BUF) do { \
        f16x8 af, bf[4]; \
        af = *(const f16x8*)&As[kh][BUF][(w4 * 16 + l16) * 32 + quad * 8]; \
        _Pragma("unroll") \
        for (int nt = 0; nt < 4; nt++) \
            bf[nt] = *(const f16x8*)&Bs[kh][BUF][(nt * 16 + l16) * 32 + quad * 8]; \
        _Pragma("unroll") \
        for (int nt = 0; nt < 4; nt++) \
            acc[nt] = __builtin_amdgcn_mfma_f32_16x16x32_f16(af, bf[nt], acc[nt], 0, 0, 0); } while (0)

    f32x4 acc[4];
#pragma unroll
    for (int nt = 0; nt < 4; nt++) acc[nt] = (f32x4){0.f, 0.f, 0.f, 0.f};

    // prologue: 2 tiles in flight (4 loads per wave)
    GISSUE(0, 0); GISSUE(1, 1);
    for (int kt = 0; kt < 33; kt++) {
        // per-wave: wait tile kt (oldest 2 of 4); tile kt+1 stays in flight
        asm volatile("s_waitcnt vmcnt(2) lgkmcnt(0)\n\ts_barrier" ::: "memory");
        GISSUE(kt + 2, (kt + 2) % 3);
        GCOMPUTE(kt % 3);
    }
    asm volatile("s_waitcnt vmcnt(2) lgkmcnt(0)\n\ts_barrier" ::: "memory");
    GCOMPUTE(0);   // kt=33 -> 33%3=0
    asm volatile("s_waitcnt vmcnt(0) lgkmcnt(0)\n\ts_barrier" ::: "memory");
    GCOMPUTE(1);   // kt=34 -> 34%3=1

    // ---- combine K-halves via LDS scratch
    if (kh == 1) {
#pragma unroll
        for (int nt = 0; nt < 4; nt++)
#pragma unroll
            for (int rr = 0; rr < 4; rr++)
                sc[w4][(quad * 4 + rr) * 64 + nt * 16 + l16] = acc[nt][rr];
    }
    __syncthreads();
    if (kh == 0) {
        const float NEG_LOG2E = -1.4426950408889634f;
        const float TWO_LOG2E =  2.8853900817779268f;
        const int bbv = half * 4 + w4;
#pragma unroll
        for (int nt = 0; nt < 4; nt++) {
            int col = Nbase + nt * 16 + l16;
            float bvv = bias[col] + (col < 512 ? bhh[col] : 0.0f);   // fold b_hh into r,z
            float scl = (col < 512) ? NEG_LOG2E : TWO_LOG2E;
            int gs = col >> 8, hcc = col & 255;
            int gw = hcc >> 5, gtc = (hcc >> 4) & 1, gl = hcc & 15;
            int u = gs * 2 + gtc;
            int gtid = gw * 64 + quad * 16 + gl;
            size_t off = ((size_t)((t * 8 + bbv) * 6 + u)) * 2048 + (size_t)gtid * 4;
            f16x4 st;
#pragma unroll
            for (int rr = 0; rr < 4; rr++) {
                float v = acc[nt][rr] + sc[w4][(quad * 4 + rr) * 64 + nt * 16 + l16];
                st[rr] = (f16)((v + bvv) * scl);
            }
            *(f16x4*)(Cgi + off) = st;
        }
    }
#undef GISSUE
#undef GCOMPUTE
}

// ---------------------------------------------------------------- K3: GRU scan (round-9 8-wave version)
// W_hh fragments pinned a[0:127]; accumulators in VGPRs (unified file).
#define ACLOB \
  "a0","a1","a2","a3","a4","a5","a6","a7","a8","a9","a10","a11","a12","a13","a14","a15", \
  "a16","a17","a18","a19","a20","a21","a22","a23","a24","a25","a26","a27","a28","a29","a30","a31", \
  "a32","a33","a34","a35","a36","a37","a38","a39","a40","a41","a42","a43","a44","a45","a46","a47", \
  "a48","a49","a50","a51","a52","a53","a54","a55","a56","a57","a58","a59","a60","a61","a62","a63", \
  "a64","a65","a66","a67","a68","a69","a70","a71","a72","a73","a74","a75","a76","a77","a78","a79", \
  "a80","a81","a82","a83","a84","a85","a86","a87","a88","a89","a90","a91","a92","a93","a94","a95", \
  "a96","a97","a98","a99","a100","a101","a102","a103","a104","a105","a106","a107","a108","a109","a110","a111", \
  "a112","a113","a114","a115","a116","a117","a118","a119","a120","a121","a122","a123","a124","a125","a126","a127"

#define LF8(A0,A1, U, KT) do { \
  f32x2 _t = *(const f32x2*)(whh8 + (size_t)(((U) >> 1) * 256 + wid * 32 + ((U) & 1) * 16 + l16) * 256 + (KT) * 32 + quad * 8); \
  asm volatile("v_accvgpr_write_b32 a" #A0 ", %0\n\t" \
               "v_accvgpr_write_b32 a" #A1 ", %1" \
               :: "v"(_t[0]), "v"(_t[1]) : "a" #A0, "a" #A1); } while (0)

#define LFN(A0,A1,A2,A3, TC, KT) do { \
  f32x4 _t = *(const f32x4*)(whh16 + (size_t)(512 + wid * 32 + (TC) * 16 + l16) * 256 + (KT) * 32 + quad * 8); \
  asm volatile("v_accvgpr_write_b32 a" #A0 ", %0\n\t" \
               "v_accvgpr_write_b32 a" #A1 ", %1\n\t" \
               "v_accvgpr_write_b32 a" #A2 ", %2\n\t" \
               "v_accvgpr_write_b32 a" #A3 ", %3" \
               :: "v"(_t[0]), "v"(_t[1]), "v"(_t[2]), "v"(_t[3]) \
               : "a" #A0, "a" #A1, "a" #A2, "a" #A3); } while (0)

// fp8 gate MFMA groups: accumulators %[aR0],%[aR1],%[aZ0],%[aZ1] (VGPR quads)
#define FP8GZ(P, F0,F1,F2,F3) \
  "v_mfma_f32_16x16x32_fp8_fp8 %[aR0], " P ", a[" F0 "], %[zq]\n\t" \
  "v_mfma_f32_16x16x32_fp8_fp8 %[aR1], " P ", a[" F1 "], %[zq]\n\t" \
  "v_mfma_f32_16x16x32_fp8_fp8 %[aZ0], " P ", a[" F2 "], %[zq]\n\t" \
  "v_mfma_f32_16x16x32_fp8_fp8 %[aZ1], " P ", a[" F3 "], %[zq]\n\t"

#define FP8G(P, F0,F1,F2,F3) \
  "v_mfma_f32_16x16x32_fp8_fp8 %[aR0], " P ", a[" F0 "], %[aR0]\n\t" \
  "v_mfma_f32_16x16x32_fp8_fp8 %[aR1], " P ", a[" F1 "], %[aR1]\n\t" \
  "v_mfma_f32_16x16x32_fp8_fp8 %[aZ0], " P ", a[" F2 "], %[aZ0]\n\t" \
  "v_mfma_f32_16x16x32_fp8_fp8 %[aZ1], " P ", a[" F3 "], %[aZ1]\n\t"

#define F16GZ(Q, G0,G1) \
  "v_mfma_f32_16x16x32_f16 %[aN0], " Q ", a[" G0 "], %[zq]\n\t" \
  "v_mfma_f32_16x16x32_f16 %[aN1], " Q ", a[" G1 "], %[zq]\n\t"

#define F16G(Q, G0,G1) \
  "v_mfma_f32_16x16x32_f16 %[aN0], " Q ", a[" G0 "], %[aN0]\n\t" \
  "v_mfma_f32_16x16x32_f16 %[aN1], " Q ", a[" G1 "], %[aN1]\n\t"

__global__ __launch_bounds__(512, 2) void gru_kernel(const f16* __restrict__ gi,
                                                     const f16* __restrict__ whh16,
                                                     const uint8_t* __restrict__ whh8,
                                                     const float* __restrict__ b_hh,
                                                     const float* __restrict__ W_out,
                                                     const float* __restrict__ b_out,
                                                     float* __restrict__ out) {
    __shared__ __align__(16) f16 hbufF[2][16 * 280];      // f16 h (n-gate A + head)
    __shared__ __align__(16) uint8_t hbuf8[2][16 * 272];  // fp8 h (rz A)
    const int tid = threadIdx.x, lane = tid & 63, wid = tid >> 6;   // wid 0..7
    const int quad = lane >> 4, l16 = lane & 15;
    const int bb = blockIdx.x;

    for (int i = tid; i < 16 * 280; i += 512) hbufF[1][i] = (f16)0.0f;
    for (int i = tid; i < 16 * 272; i += 512) hbuf8[1][i] = 0;

    LF8(0,1, 0,0);   LF8(2,3, 0,1);   LF8(4,5, 0,2);   LF8(6,7, 0,3);
    LF8(8,9, 0,4);   LF8(10,11, 0,5); LF8(12,13, 0,6); LF8(14,15, 0,7);
    LF8(16,17, 1,0); LF8(18,19, 1,1); LF8(20,21, 1,2); LF8(22,23, 1,3);
    LF8(24,25, 1,4); LF8(26,27, 1,5); LF8(28,29, 1,6); LF8(30,31, 1,7);
    LF8(32,33, 2,0); LF8(34,35, 2,1); LF8(36,37, 2,2); LF8(38,39, 2,3);
    LF8(40,41, 2,4); LF8(42,43, 2,5); LF8(44,45, 2,6); LF8(46,47, 2,7);
    LF8(48,49, 3,0); LF8(50,51, 3,1); LF8(52,53, 3,2); LF8(54,55, 3,3);
    LF8(56,57, 3,4); LF8(58,59, 3,5); LF8(60,61, 3,6); LF8(62,63, 3,7);
    LFN(64,65,66,67,   0,0); LFN(68,69,70,71,   0,1); LFN(72,73,74,75,   0,2); LFN(76,77,78,79,   0,3);
    LFN(80,81,82,83,   0,4); LFN(84,85,86,87,   0,5); LFN(88,89,90,91,   0,6); LFN(92,93,94,95,   0,7);
    LFN(96,97,98,99,   1,0); LFN(100,101,102,103, 1,1); LFN(104,105,106,107, 1,2); LFN(108,109,110,111, 1,3);
    LFN(112,113,114,115, 1,4); LFN(116,117,118,119, 1,5); LFN(120,121,122,123, 1,6); LFN(124,125,126,127, 1,7);

    const float C2 = 2.8853900817779268f;   // 2*log2e
    float bhn[2];
#pragma unroll
    for (int tc = 0; tc < 2; tc++) bhn[tc] = C2 * b_hh[512 + wid * 32 + tc * 16 + l16];
    float hm[2][4];
#pragma unroll
    for (int tc = 0; tc < 2; tc++)
#pragma unroll
        for (int rr = 0; rr < 4; rr++) hm[tc][rr] = 0.f;

    uint32_t aF0 = (uint32_t)(uintptr_t)(__attribute__((address_space(3))) const void*)
                       (&hbufF[0][l16 * 280 + quad * 8]);
    uint32_t aF1 = (uint32_t)(uintptr_t)(__attribute__((address_space(3))) const void*)
                       (&hbufF[1][l16 * 280 + quad * 8]);
    uint32_t a80 = (uint32_t)(uintptr_t)(__attribute__((address_space(3))) const void*)
                       (&hbuf8[0][l16 * 272 + quad * 8]);
    uint32_t a81 = (uint32_t)(uintptr_t)(__attribute__((address_space(3))) const void*)
                       (&hbuf8[1][l16 * 272 + quad * 8]);

    // coalesced gi: per (t,bb) slab = 12288 f16; chunk u at u*2048; thread at tid*4
    const size_t lanebase = (size_t)bb * 12288 + (size_t)tid * 4;
    f16x4 gcur[6];
#pragma unroll
    for (int u = 0; u < 6; u++)
        gcur[u] = *(const f16x4*)(gi + lanebase + u * 2048);

    const f32x4 zq = (f32x4){0.f, 0.f, 0.f, 0.f};

    BAR_LDS();

    for (int t = 0; t < 31; t++) {
        const uint32_t a8 = (t & 1) ? a80 : a81;
        const uint32_t aF = (t & 1) ? aF0 : aF1;
        f32x4 aR0, aR1, aZ0, aZ1, aN0, aN1;
        f32x2 p0, p1, p2;
        f32x4 q0, q1, q2;
        asm volatile(
            "s_setprio 1\n\t"
            "ds_read_b64  %[p0], %[a8] offset:0\n\t"
            "ds_read_b128 %[q0], %[aF] offset:0\n\t"
            "ds_read_b64  %[p1], %[a8] offset:32\n\t"
            "ds_read_b128 %[q1], %[aF] offset:64\n\t"
            "ds_read_b64  %[p2], %[a8] offset:64\n\t"
            "ds_read_b128 %[q2], %[aF] offset:128\n\t"
            "s_waitcnt lgkmcnt(5)\n\t"
            FP8GZ("%[p0]", "0:1","16:17","32:33","48:49")
            "ds_read_b64  %[p0], %[a8] offset:96\n\t"
            "s_waitcnt lgkmcnt(5)\n\t"
            F16GZ("%[q0]", "64:67","96:99")
            "ds_read_b128 %[q0], %[aF] offset:192\n\t"
            "s_waitcnt lgkmcnt(5)\n\t"
            FP8G("%[p1]", "2:3","18:19","34:35","50:51")
            "ds_read_b64  %[p1], %[a8] offset:128\n\t"
            "s_waitcnt lgkmcnt(5)\n\t"
            F16G("%[q1]", "68:71","100:103")
            "ds_read_b128 %[q1], %[aF] offset:256\n\t"
            "s_waitcnt lgkmcnt(5)\n\t"
            FP8G("%[p2]", "4:5","20:21","36:37","52:53")
            "ds_read_b64  %[p2], %[a8] offset:160\n\t"
            "s_waitcnt lgkmcnt(5)\n\t"
            F16G("%[q2]", "72:75","104:107")
            "ds_read_b128 %[q2], %[aF] offset:320\n\t"
            "s_waitcnt lgkmcnt(5)\n\t"
            FP8G("%[p0]", "6:7","22:23","38:39","54:55")
            "ds_read_b64  %[p0], %[a8] offset:192\n\t"
            "s_waitcnt lgkmcnt(5)\n\t"
            F16G("%[q0]", "76:79","108:111")
            "ds_read_b128 %[q0], %[aF] offset:384\n\t"
            "s_waitcnt lgkmcnt(5)\n\t"
            FP8G("%[p1]", "8:9","24:25","40:41","56:57")
            "ds_read_b64  %[p1], %[a8] offset:224\n\t"
            "s_waitcnt lgkmcnt(5)\n\t"
            F16G("%[q1]", "80:83","112:115")
            "ds_read_b128 %[q1], %[aF] offset:448\n\t"
            "s_waitcnt lgkmcnt(5)\n\t"
            FP8G("%[p2]", "10:11","26:27","42:43","58:59")
            "s_waitcnt lgkmcnt(4)\n\t"
            F16G("%[q2]", "84:87","116:119")
            "s_waitcnt lgkmcnt(3)\n\t"
            FP8G("%[p0]", "12:13","28:29","44:45","60:61")
            "s_waitcnt lgkmcnt(2)\n\t"
            F16G("%[q0]", "88:91","120:123")
            "s_waitcnt lgkmcnt(1)\n\t"
            FP8G("%[p1]", "14:15","30:31","46:47","62:63")
            "s_waitcnt lgkmcnt(0)\n\t"
            F16G("%[q1]", "92:95","124:127")
            "s_setprio 0\n\t"
            "s_nop 7\n\ts_nop 7"
            : [aR0]"=&v"(aR0), [aR1]"=&v"(aR1), [aZ0]"=&v"(aZ0), [aZ1]"=&v"(aZ1),
              [aN0]"=&v"(aN0), [aN1]"=&v"(aN1),
              [p0]"=&v"(p0), [p1]"=&v"(p1), [p2]"=&v"(p2),
              [q0]"=&v"(q0), [q1]"=&v"(q1), [q2]"=&v"(q2)
            : [a8]"v"(a8), [aF]"v"(aF), [zq]"v"(zq)
            : ACLOB);

        // gate math (exp2 form): accR/accZ are rz matmul (x1/16), accN is n matmul
        f16* hdF = hbufF[t & 1];
        uint8_t* hd8 = hbuf8[t & 1];
        const float C1N16 = -0.09016844005556021f;   // -log2e/16
#pragma unroll
        for (int tc = 0; tc < 2; tc++) {
            const int hcx = wid * 32 + tc * 16 + l16;
            const f32x4 vR = tc ? aR1 : aR0;
            const f32x4 vZ = tc ? aZ1 : aZ0;
            const f32x4 vN = tc ? aN1 : aN0;
#pragma unroll
            for (int rr = 0; rr < 4; rr++) {
                float rg = frcp(1.f + fexp2(fmaf(C1N16, vR[rr], (float)gcur[tc][rr])));
                float zg = frcp(1.f + fexp2(fmaf(C1N16, vZ[rr], (float)gcur[2 + tc][rr])));
                float t2 = fmaf(rg, fmaf(C2, vN[rr], bhn[tc]), (float)gcur[4 + tc][rr]);
                float e2 = fexp2(t2);
                float ng = fmaf(-2.f, frcp(e2 + 1.f), 1.f);   // tanh
                float h  = fmaf(zg, hm[tc][rr] - ng, ng);     // (1-z)n + z*h
                hm[tc][rr] = h;
                hdF[(quad * 4 + rr) * 280 + hcx] = (f16)h;
                int pk = __builtin_amdgcn_cvt_pk_fp8_f32(h, h, 0, false);
                hd8[(quad * 4 + rr) * 272 + hcx] = (uint8_t)pk;
            }
        }
        // prefetch gi for t+1 (registers; survives lgkm-only barrier)
        {
            int tn = (t < 30) ? t + 1 : 30;
            const f16* gsrc = gi + (size_t)tn * 98304 + lanebase;
#pragma unroll
            for (int u = 0; u < 6; u++)
                gcur[u] = *(const f16x4*)(gsrc + u * 2048);
        }
        BAR_LDS();
    }
    // output head: final h in hbufF[0]
    if (tid < 160) {
        int r = tid / 10, oc = tid - r * 10;
        const f16* hfin = hbufF[0];
        float s = b_out[oc];
        for (int k = 0; k < 256; k++) s += (float)hfin[r * 280 + k] * W_out[oc * 256 + k];
        out[(bb * 16 + r) * 10 + oc] = frcp(1.f + __expf(-s));
    }
}

// ---------------------------------------------------------------- launch
extern "C" void kernel_launch(void* const* d_in, const int* in_sizes, int n_in,
                              void* d_out, int out_size, void* d_ws, size_t ws_size,
                              hipStream_t stream) {
    const float* x     = (const float*)d_in[0];
    const float* W_aug = (const float*)d_in[1];
    // d_in[2] = b_aug — cancels in dx, unused
    const float* W_ih  = (const float*)d_in[3];
    const float* W_hh  = (const float*)d_in[4];
    const float* b_ih  = (const float*)d_in[5];
    const float* b_hh  = (const float*)d_in[6];
    const float* W_out = (const float*)d_in[7];
    const float* b_out = (const float*)d_in[8];
    float* out = (float*)d_out;

    char* ws = (char*)d_ws;
    const size_t SIG_BYTES  = (size_t)3968 * 2240 * 2;           // 17,776,640
    const size_t WIH_BYTES  = (size_t)768 * 2240 * 2;            //  3,440,640
    const size_t WHH_BYTES  = (size_t)768 * 256 * 2;             //    393,216
    const size_t WHH8_BYTES = (size_t)512 * 256;                 //    131,072
    const size_t GI_BYTES   = (size_t)31 * 8 * 6 * 512 * 4 * 2;  //  6,094,848
    if (ws_size < SIG_BYTES + WIH_BYTES + WHH_BYTES + WHH8_BYTES + GI_BYTES) return;
    f16* sig16    = (f16*)ws;
    f16* wih16    = (f16*)(ws + SIG_BYTES);
    f16* whh16    = (f16*)(ws + SIG_BYTES + WIH_BYTES);
    uint8_t* whh8 = (uint8_t*)(ws + SIG_BYTES + WIH_BYTES + WHH_BYTES);
    f16* giw      = (f16*)(ws + SIG_BYTES + WIH_BYTES + WHH_BYTES + WHH8_BYTES);

    hipLaunchKernelGGL(prep_kernel, dim3(2920), dim3(256), 0, stream,
                       x, W_aug, W_ih, W_hh, sig16, wih16, whh16, whh8);
    hipLaunchKernelGGL(gemm_kernel, dim3(744), dim3(512), 0, stream,
                       sig16, wih16, b_ih, b_hh, giw);
    hipLaunchKernelGGL(gru_kernel, dim3(8), dim3(512), 0, stream,
                       giw, whh16, whh8, b_hh, W_out, b_out, out);
}

// Round 12
// 185.797 us; speedup vs baseline: 1.0723x; 1.0516x over previous
//
#include <hip/hip_runtime.h>
#include <hip/hip_bf16.h>
#include <stdint.h>

// Problem constants
// B=128 STREAM=512 IN_CH=4 EXTRA=5 GROUPS=2 DEPTH=3 STEP=16 LENGTH=32 RNN=256 OUT=10
// C=10 SIG_C=1110 W=31 F=2220, padded K = 2240, GEMM M = 31*128 = 3968, N = 768
// gi layout (f16, COALESCED): chunk u of thread gtid at step (t,bb):
//   f16 offset = ((t*8+bb)*6 + u)*2048 + gtid*4,  u = gs*2+gtc in [0,6)
// gi VALUES pre-scaled for exp2-based gate math:
//   r,z chunks: -log2e*(gemm + b_ih + b_hh);  n chunks: 2*log2e*(gemm + b_ih)
// GEMM: in-block split-K (round-11 config, frozen: best total 195.4).
// GRU (round 12): rz gates via v_mfma_f32_16x16x128_f8f6f4 (K=128, MX rate):
//   per-CU MFMA cycles/step 1864 -> 1174 (rz 32xK32 -> 8xK128). Weights stay
//   in the SAME row-major whh8 buffer (contiguous 32B/lane = one K=128 frag:
//   k = kf*128 + quad*32 + byte; identical packing on A and B sides so the
//   internal k-permutation cancels). h fp8 A-frags read as 4x b128 from
//   hbuf8[l16*272 + kf*128 + quad*32]. n gate unchanged (f16, K=32 chain).
//   rz weight AGPRs a[0:63] (8 regs/frag x 2gates x 2cols x 2kf); n a[64:127].
// prep: unchanged.

typedef _Float16 f16;
typedef f16  f16x2 __attribute__((ext_vector_type(2)));
typedef f16  f16x4 __attribute__((ext_vector_type(4)));
typedef f16  f16x8 __attribute__((ext_vector_type(8)));
typedef float f32x2 __attribute__((ext_vector_type(2)));
typedef float f32x4 __attribute__((ext_vector_type(4)));
typedef float f32x8 __attribute__((ext_vector_type(8)));

#define ASYNC16(gp, lp) __builtin_amdgcn_global_load_lds( \
    (const __attribute__((address_space(1))) void*)(gp),  \
    (__attribute__((address_space(3))) void*)(lp), 16, 0, 0)

#define BAR_LDS() do { asm volatile("s_waitcnt lgkmcnt(0)" ::: "memory"); \
                       __builtin_amdgcn_s_barrier();                      \
                       asm volatile("" ::: "memory"); } while (0)

__device__ __forceinline__ float fexp2(float x) {
    float r; asm("v_exp_f32 %0, %1" : "=v"(r) : "v"(x)); return r;
}
__device__ __forceinline__ float frcp(float x) {
    float r; asm("v_rcp_f32 %0, %1" : "=v"(r) : "v"(x)); return r;
}

// ---------------------------------------------------------------- K0: prep
// blocks [0,840):    W_ih f32 -> f16 (pad 2220->2240), 8 elems/thread
// blocks [840,936):  W_hh f32 -> f16 (all) + fp8*16 (r,z rows), 8 elems/thread
// blocks [936,2920): signature chains, 4/block; LDS-staged coalesced row store
__global__ __launch_bounds__(256) void prep_kernel(const float* __restrict__ x,
                                                   const float* __restrict__ W_aug,
                                                   const float* __restrict__ Wih,
                                                   const float* __restrict__ Whh,
                                                   f16* __restrict__ sig16,
                                                   f16* __restrict__ wih16,
                                                   f16* __restrict__ whh16,
                                                   uint8_t* __restrict__ whh8) {
    __shared__ float dxs[4][31][10];
    __shared__ f16 srow[4][1112];                  // per-chain staging (1110 + pad)
    const int tid = threadIdx.x;
    if (blockIdx.x < 840) {
        int c = blockIdx.x * 256 + tid;          // chunk 0..215039
        int r = c / 280, kc = (c - r * 280) * 8;
        const float* src = Wih + (size_t)r * 2220 + kc;
        f16x8 o;
        if (kc + 8 <= 2220) {
            float4 v0 = *(const float4*)(src);
            float4 v1 = *(const float4*)(src + 4);
            o[0]=(f16)v0.x; o[1]=(f16)v0.y; o[2]=(f16)v0.z; o[3]=(f16)v0.w;
            o[4]=(f16)v1.x; o[5]=(f16)v1.y; o[6]=(f16)v1.z; o[7]=(f16)v1.w;
        } else {
#pragma unroll
            for (int j = 0; j < 8; j++)
                o[j] = (f16)((kc + j < 2220) ? src[j] : 0.0f);
        }
        *(f16x8*)(wih16 + (size_t)r * 2240 + kc) = o;
        return;
    }
    if (blockIdx.x < 936) {
        int c2 = ((int)blockIdx.x - 840) * 256 + tid;    // 0..24575
        int j8 = c2 * 8;
        float w[8];
        {
            float4 v0 = *(const float4*)(Whh + j8);
            float4 v1 = *(const float4*)(Whh + j8 + 4);
            w[0]=v0.x; w[1]=v0.y; w[2]=v0.z; w[3]=v0.w;
            w[4]=v1.x; w[5]=v1.y; w[6]=v1.z; w[7]=v1.w;
        }
        f16x8 o;
#pragma unroll
        for (int j = 0; j < 8; j++) o[j] = (f16)w[j];
        *(f16x8*)(whh16 + j8) = o;
        if (j8 < 131072) {                       // r,z gate rows -> fp8 e4m3 (x16)
            uint32_t p01 = (uint32_t)__builtin_amdgcn_cvt_pk_fp8_f32(w[0]*16.f, w[1]*16.f, 0, false) & 0xffffu;
            uint32_t p23 = (uint32_t)__builtin_amdgcn_cvt_pk_fp8_f32(w[2]*16.f, w[3]*16.f, 0, false) & 0xffffu;
            uint32_t p45 = (uint32_t)__builtin_amdgcn_cvt_pk_fp8_f32(w[4]*16.f, w[5]*16.f, 0, false) & 0xffffu;
            uint32_t p67 = (uint32_t)__builtin_amdgcn_cvt_pk_fp8_f32(w[6]*16.f, w[7]*16.f, 0, false) & 0xffffu;
            uint2 st = make_uint2(p01 | (p23 << 16), p45 | (p67 << 16));
            *(uint2*)(whh8 + j8) = st;
        }
        return;
    }
    // ---- signature chains (block-uniform branch; __syncthreads safe)
    const int sub = tid >> 6, t64 = tid & 63;
    const int cid = ((int)blockIdx.x - 936) * 4 + sub;   // 0..7935
    const int w = cid % 31;
    const int bg = cid / 31;
    const int b = bg >> 1, g = bg & 1;
    if (t64 < 31) {
        int s = w * 16 + t64;
        const float4 x0 = *(const float4*)(x + ((size_t)b * 512 + s) * 4);
        const float4 x1 = *(const float4*)(x + ((size_t)b * 512 + s + 1) * 4);
        float d0 = x1.x - x0.x, d1 = x1.y - x0.y, d2 = x1.z - x0.z, d3 = x1.w - x0.w;
        dxs[sub][t64][0] = d0; dxs[sub][t64][1] = d1;
        dxs[sub][t64][2] = d2; dxs[sub][t64][3] = d3;
        dxs[sub][t64][4] = 1.0f / 511.0f;
#pragma unroll
        for (int e = 0; e < 5; e++) {
            const float* wa = W_aug + (g * 5 + e) * 4;
            dxs[sub][t64][5 + e] = d0 * wa[0] + d1 * wa[1] + d2 * wa[2] + d3 * wa[3];
        }
    }
    __syncthreads();
    size_t base = ((size_t)(w * 128 + b)) * 2240 + (size_t)g * 1110;
    if (t64 < 50) {
        int p0 = 2 * t64, p1 = p0 + 1;
        int i0 = p0 / 10, j0 = p0 % 10, j1 = j0 + 1;   // p0 even -> j1 <= 9
        const float* dz  = &dxs[sub][0][0];
        const float* pI  = dz + i0;
        const float* pJ0 = dz + j0;
        const float* pJ1 = dz + j1;
        float s3a[10], s3b[10];
#pragma unroll
        for (int k = 0; k < 10; k++) { s3a[k] = 0.f; s3b[k] = 0.f; }
        float s2a = 0.f, s2b = 0.f, s1 = 0.f;
        for (int l = 0; l < 31; l++) {
            const float* row = dz + l * 10;
            float di  = pI[l * 10];
            float dj0 = pJ0[l * 10];
            float dj1 = pJ1[l * 10];
            float t0 = s1 + di * (1.0f / 3.0f);
            float a0 = s2a + t0 * (0.5f * dj0);
            float a1 = s2b + t0 * (0.5f * dj1);
#pragma unroll
            for (int k = 0; k < 10; k++) {
                float dk = row[k];
                s3a[k] += a0 * dk;
                s3b[k] += a1 * dk;
            }
            float u = s1 + 0.5f * di;
            s2a += u * dj0;
            s2b += u * dj1;
            s1 += di;
        }
        *(f16x2*)&srow[sub][10 + p0] = (f16x2){(f16)s2a, (f16)s2b};
#pragma unroll
        for (int k = 0; k < 5; k++)
            *(f16x2*)&srow[sub][110 + p0 * 10 + 2 * k] =
                (f16x2){(f16)s3a[2 * k], (f16)s3a[2 * k + 1]};
#pragma unroll
        for (int k = 0; k < 5; k++)
            *(f16x2*)&srow[sub][110 + p1 * 10 + 2 * k] =
                (f16x2){(f16)s3b[2 * k], (f16)s3b[2 * k + 1]};
    } else if (t64 < 60) {
        int c = t64 - 50;
        const float* pc = &dxs[sub][0][0] + c;
        float s = 0.f;
        for (int l = 0; l < 31; l++) s += pc[l * 10];
        srow[sub][c] = (f16)s;
    }
    __syncthreads();
    for (int j = t64; j < 555; j += 64)
        *(f16x2*)(sig16 + base + 2 * j) = *(const f16x2*)&srow[sub][2 * j];
    if (g == 1 && t64 < 10)
        *(f16x2*)(sig16 + ((size_t)(w * 128 + b)) * 2240 + 2220 + 2 * t64) =
            (f16x2){(f16)0.0f, (f16)0.0f};
}

// ---------------------------------------------------------------- K2: gi = sig @ W_ih.T + biases (f16, coalesced GRU layout)
// 64x64 tile, 744 blocks x 512 thr; in-block split-K; LDS-scratch combine.
__global__ __launch_bounds__(512) void gemm_kernel(const f16* __restrict__ A,     // 3968 x 2240
                                                   const f16* __restrict__ Bw,    // 768 x 2240 f16
                                                   const float* __restrict__ bias,
                                                   const float* __restrict__ bhh,
                                                   f16* __restrict__ Cgi) {
    const int lin = blockIdx.x;          // 744 = 62 mb x 12 nc
    const int nc = lin % 12;
    const int mb = lin / 12;             // 0..61
    const int t = mb >> 1, half = mb & 1;
    __shared__ __align__(16) f16 As[2][3][64 * 32];   // 24 KB
    __shared__ __align__(16) f16 Bs[2][3][64 * 32];   // 24 KB
    __shared__ __align__(16) float sc[4][16 * 64];    // 16 KB (total 64 KB -> 2 blocks/CU)
    const int tid = threadIdx.x, lane = tid & 63, wid = tid >> 6;   // wid 0..7
    const int kh = wid >> 2, w4 = wid & 3;            // K-half, wave-in-half
    const int l16 = lane & 15, quad = lane >> 4;
    const int lrow = lane >> 2, lk = lane & 3;
    const int Nbase = nc * 64;
    const f16* gaA = A  + (size_t)(mb * 64 + w4 * 16 + lrow) * 2240 + kh * 1120 + lk * 8;
    const f16* gbB = Bw + (size_t)(Nbase + w4 * 16 + lrow) * 2240 + kh * 1120 + lk * 8;

#define GISSUE(KT, BUF) do { \
        int _k0 = (KT) * 32; \
        ASYNC16(gaA + _k0, &As[kh][BUF][(w4 * 16) * 32]); \
        ASYNC16(gbB + _k0, &Bs[kh][BUF][(w4 * 16) * 32]); } while (0)

#define GCOMPUTE(BUF) do { \
        f16x8 af, bf[4]; \
        af = *(const f16x8*)&As[kh][BUF][(w4 * 16 + l16) * 32 + quad * 8]; \
        _Pragma("unroll") \
        for (int nt = 0; nt < 4; nt++) \
            bf[nt] = *(const f16x8*)&Bs[kh][BUF][(nt * 16 + l16) * 32 + quad * 8]; \
        _Pragma("unroll") \
        for (int nt = 0; nt < 4; nt++) \
            acc[nt] = __builtin_amdgcn_mfma_f32_16x16x32_f16(af, bf[nt], acc[nt], 0, 0, 0); } while (0)

    f32x4 acc[4];
#pragma unroll
    for (int nt = 0; nt < 4; nt++) acc[nt] = (f32x4){0.f, 0.f, 0.f, 0.f};

    GISSUE(0, 0); GISSUE(1, 1);
    for (int kt = 0; kt < 33; kt++) {
        asm volatile("s_waitcnt vmcnt(2) lgkmcnt(0)\n\ts_barrier" ::: "memory");
        GISSUE(kt + 2, (kt + 2) % 3);
        GCOMPUTE(kt % 3);
    }
    asm volatile("s_waitcnt vmcnt(2) lgkmcnt(0)\n\ts_barrier" ::: "memory");
    GCOMPUTE(0);   // kt=33
    asm volatile("s_waitcnt vmcnt(0) lgkmcnt(0)\n\ts_barrier" ::: "memory");
    GCOMPUTE(1);   // kt=34

    // ---- combine K-halves via LDS scratch
    if (kh == 1) {
#pragma unroll
        for (int nt = 0; nt < 4; nt++)
#pragma unroll
            for (int rr = 0; rr < 4; rr++)
                sc[w4][(quad * 4 + rr) * 64 + nt * 16 + l16] = acc[nt][rr];
    }
    __syncthreads();
    if (kh == 0) {
        const float NEG_LOG2E = -1.4426950408889634f;
        const float TWO_LOG2E =  2.8853900817779268f;
        const int bbv = half * 4 + w4;
#pragma unroll
        for (int nt = 0; nt < 4; nt++) {
            int col = Nbase + nt * 16 + l16;
            float bvv = bias[col] + (col < 512 ? bhh[col] : 0.0f);   // fold b_hh into r,z
            float scl = (col < 512) ? NEG_LOG2E : TWO_LOG2E;
            int gs = col >> 8, hcc = col & 255;
            int gw = hcc >> 5, gtc = (hcc >> 4) & 1, gl = hcc & 15;
            int u = gs * 2 + gtc;
            int gtid = gw * 64 + quad * 16 + gl;
            size_t off = ((size_t)((t * 8 + bbv) * 6 + u)) * 2048 + (size_t)gtid * 4;
            f16x4 st;
#pragma unroll
            for (int rr = 0; rr < 4; rr++) {
                float v = acc[nt][rr] + sc[w4][(quad * 4 + rr) * 64 + nt * 16 + l16];
                st[rr] = (f16)((v + bvv) * scl);
            }
            *(f16x4*)(Cgi + off) = st;
        }
    }
#undef GISSUE
#undef GCOMPUTE
}

// ---------------------------------------------------------------- K3: GRU scan
// rz: K=128 fp8 MFMA, weights a[0:63] (8 regs/frag); n: f16 K=32, a[64:127].
#define ACLOB_RZ \
  "a0","a1","a2","a3","a4","a5","a6","a7","a8","a9","a10","a11","a12","a13","a14","a15", \
  "a16","a17","a18","a19","a20","a21","a22","a23","a24","a25","a26","a27","a28","a29","a30","a31", \
  "a32","a33","a34","a35","a36","a37","a38","a39","a40","a41","a42","a43","a44","a45","a46","a47", \
  "a48","a49","a50","a51","a52","a53","a54","a55","a56","a57","a58","a59","a60","a61","a62","a63"

#define ACLOB_N \
  "a64","a65","a66","a67","a68","a69","a70","a71","a72","a73","a74","a75","a76","a77","a78","a79", \
  "a80","a81","a82","a83","a84","a85","a86","a87","a88","a89","a90","a91","a92","a93","a94","a95", \
  "a96","a97","a98","a99","a100","a101","a102","a103","a104","a105","a106","a107","a108","a109","a110","a111", \
  "a112","a113","a114","a115","a116","a117","a118","a119","a120","a121","a122","a123","a124","a125","a126","a127"

// one K=128 fp8 weight fragment (16 gate cols x 128 k) -> 8 AGPRs
#define LF8X(A0,A1,A2,A3,A4,A5,A6,A7, G, TC, KF) do { \
  const uint8_t* _p = whh8 + (size_t)((G) * 256 + wid * 32 + (TC) * 16 + l16) * 256 + (KF) * 128 + quad * 32; \
  f32x4 _t0 = *(const f32x4*)_p; \
  f32x4 _t1 = *(const f32x4*)(_p + 16); \
  asm volatile("v_accvgpr_write_b32 a" #A0 ", %0\n\t" \
               "v_accvgpr_write_b32 a" #A1 ", %1\n\t" \
               "v_accvgpr_write_b32 a" #A2 ", %2\n\t" \
               "v_accvgpr_write_b32 a" #A3 ", %3\n\t" \
               "v_accvgpr_write_b32 a" #A4 ", %4\n\t" \
               "v_accvgpr_write_b32 a" #A5 ", %5\n\t" \
               "v_accvgpr_write_b32 a" #A6 ", %6\n\t" \
               "v_accvgpr_write_b32 a" #A7 ", %7" \
               :: "v"(_t0[0]), "v"(_t0[1]), "v"(_t0[2]), "v"(_t0[3]), \
                  "v"(_t1[0]), "v"(_t1[1]), "v"(_t1[2]), "v"(_t1[3]) \
               : "a" #A0, "a" #A1, "a" #A2, "a" #A3, \
                 "a" #A4, "a" #A5, "a" #A6, "a" #A7); } while (0)

#define LFN(A0,A1,A2,A3, TC, KT) do { \
  f32x4 _t = *(const f32x4*)(whh16 + (size_t)(512 + wid * 32 + (TC) * 16 + l16) * 256 + (KT) * 32 + quad * 8); \
  asm volatile("v_accvgpr_write_b32 a" #A0 ", %0\n\t" \
               "v_accvgpr_write_b32 a" #A1 ", %1\n\t" \
               "v_accvgpr_write_b32 a" #A2 ", %2\n\t" \
               "v_accvgpr_write_b32 a" #A3 ", %3" \
               :: "v"(_t[0]), "v"(_t[1]), "v"(_t[2]), "v"(_t[3]) \
               : "a" #A0, "a" #A1, "a" #A2, "a" #A3); } while (0)

#define F16GZ(Q, G0,G1) \
  "v_mfma_f32_16x16x32_f16 %[aN0], " Q ", a[" G0 "], %[zq]\n\t" \
  "v_mfma_f32_16x16x32_f16 %[aN1], " Q ", a[" G1 "], %[zq]\n\t"

#define F16G(Q, G0,G1) \
  "v_mfma_f32_16x16x32_f16 %[aN0], " Q ", a[" G0 "], %[aN0]\n\t" \
  "v_mfma_f32_16x16x32_f16 %[aN1], " Q ", a[" G1 "], %[aN1]\n\t"

__global__ __launch_bounds__(512, 2) void gru_kernel(const f16* __restrict__ gi,
                                                     const f16* __restrict__ whh16,
                                                     const uint8_t* __restrict__ whh8,
                                                     const float* __restrict__ b_hh,
                                                     const float* __restrict__ W_out,
                                                     const float* __restrict__ b_out,
                                                     float* __restrict__ out) {
    __shared__ __align__(16) f16 hbufF[2][16 * 280];      // f16 h (n-gate A + head)
    __shared__ __align__(16) uint8_t hbuf8[2][16 * 272];  // fp8 h (rz A)
    const int tid = threadIdx.x, lane = tid & 63, wid = tid >> 6;   // wid 0..7
    const int quad = lane >> 4, l16 = lane & 15;
    const int bb = blockIdx.x;

    for (int i = tid; i < 16 * 280; i += 512) hbufF[1][i] = (f16)0.0f;
    for (int i = tid; i < 16 * 272; i += 512) hbuf8[1][i] = 0;

    // rz weights: (g, tc, kf) -> a[((g*2+tc)*2+kf)*8 .. +8)
    LF8X(0,1,2,3,4,5,6,7,         0,0,0);
    LF8X(8,9,10,11,12,13,14,15,   0,0,1);
    LF8X(16,17,18,19,20,21,22,23, 0,1,0);
    LF8X(24,25,26,27,28,29,30,31, 0,1,1);
    LF8X(32,33,34,35,36,37,38,39, 1,0,0);
    LF8X(40,41,42,43,44,45,46,47, 1,0,1);
    LF8X(48,49,50,51,52,53,54,55, 1,1,0);
    LF8X(56,57,58,59,60,61,62,63, 1,1,1);
    // n weights: f16, 8 K-frags x 2 col-frags
    LFN(64,65,66,67,   0,0); LFN(68,69,70,71,   0,1); LFN(72,73,74,75,   0,2); LFN(76,77,78,79,   0,3);
    LFN(80,81,82,83,   0,4); LFN(84,85,86,87,   0,5); LFN(88,89,90,91,   0,6); LFN(92,93,94,95,   0,7);
    LFN(96,97,98,99,   1,0); LFN(100,101,102,103, 1,1); LFN(104,105,106,107, 1,2); LFN(108,109,110,111, 1,3);
    LFN(112,113,114,115, 1,4); LFN(116,117,118,119, 1,5); LFN(120,121,122,123, 1,6); LFN(124,125,126,127, 1,7);

    const float C2 = 2.8853900817779268f;   // 2*log2e
    float bhn[2];
#pragma unroll
    for (int tc = 0; tc < 2; tc++) bhn[tc] = C2 * b_hh[512 + wid * 32 + tc * 16 + l16];
    float hm[2][4];
#pragma unroll
    for (int tc = 0; tc < 2; tc++)
#pragma unroll
        for (int rr = 0; rr < 4; rr++) hm[tc][rr] = 0.f;

    uint32_t aF0 = (uint32_t)(uintptr_t)(__attribute__((address_space(3))) const void*)
                       (&hbufF[0][l16 * 280 + quad * 8]);
    uint32_t aF1 = (uint32_t)(uintptr_t)(__attribute__((address_space(3))) const void*)
                       (&hbufF[1][l16 * 280 + quad * 8]);

    // coalesced gi: per (t,bb) slab = 12288 f16; chunk u at u*2048; thread at tid*4
    const size_t lanebase = (size_t)bb * 12288 + (size_t)tid * 4;
    f16x4 gcur[6];
#pragma unroll
    for (int u = 0; u < 6; u++)
        gcur[u] = *(const f16x4*)(gi + lanebase + u * 2048);

    const f32x4 zq = (f32x4){0.f, 0.f, 0.f, 0.f};

    BAR_LDS();

    for (int t = 0; t < 31; t++) {
        const uint32_t aF = (t & 1) ? aF0 : aF1;
        const uint8_t* hb = ((t & 1) ? hbuf8[0] : hbuf8[1]) + (size_t)l16 * 272 + quad * 32;
        f32x4 aR0, aR1, aZ0, aZ1, aN0, aN1;
        f32x4 q0, q1, q2;
        // rz A-fragments: 32B/lane per K=128 frag (kf=0 at +0, kf=1 at +128)
        f32x4 u0 = *(const f32x4*)(hb);
        f32x4 u1 = *(const f32x4*)(hb + 16);
        f32x4 u2 = *(const f32x4*)(hb + 128);
        f32x4 u3 = *(const f32x4*)(hb + 144);
        f32x8 A0f, A1f;
        A0f[0]=u0[0]; A0f[1]=u0[1]; A0f[2]=u0[2]; A0f[3]=u0[3];
        A0f[4]=u1[0]; A0f[5]=u1[1]; A0f[6]=u1[2]; A0f[7]=u1[3];
        A1f[0]=u2[0]; A1f[1]=u2[1]; A1f[2]=u2[2]; A1f[3]=u2[3];
        A1f[4]=u3[0]; A1f[5]=u3[1]; A1f[6]=u3[2]; A1f[7]=u3[3];
        __builtin_amdgcn_s_setprio(1);
        asm volatile(   // rz gates: 8 x K=128 fp8 MFMA (2-deep chains)
            "v_mfma_f32_16x16x128_f8f6f4 %[r0], %[A0], a[0:7],  %[zq]\n\t"
            "v_mfma_f32_16x16x128_f8f6f4 %[r1], %[A0], a[16:23], %[zq]\n\t"
            "v_mfma_f32_16x16x128_f8f6f4 %[z0], %[A0], a[32:39], %[zq]\n\t"
            "v_mfma_f32_16x16x128_f8f6f4 %[z1], %[A0], a[48:55], %[zq]\n\t"
            "v_mfma_f32_16x16x128_f8f6f4 %[r0], %[A1], a[8:15],  %[r0]\n\t"
            "v_mfma_f32_16x16x128_f8f6f4 %[r1], %[A1], a[24:31], %[r1]\n\t"
            "v_mfma_f32_16x16x128_f8f6f4 %[z0], %[A1], a[40:47], %[z0]\n\t"
            "v_mfma_f32_16x16x128_f8f6f4 %[z1], %[A1], a[56:63], %[z1]"
            : [r0]"=&v"(aR0), [r1]"=&v"(aR1), [z0]"=&v"(aZ0), [z1]"=&v"(aZ1)
            : [A0]"v"(A0f), [A1]"v"(A1f), [zq]"v"(zq)
            : ACLOB_RZ);
        asm volatile(   // n gate: 8 b128 reads + 16 f16 MFMA (3-deep read pipe)
            "s_waitcnt lgkmcnt(0)\n\t"
            "ds_read_b128 %[q0], %[aF] offset:0\n\t"
            "ds_read_b128 %[q1], %[aF] offset:64\n\t"
            "ds_read_b128 %[q2], %[aF] offset:128\n\t"
            "s_waitcnt lgkmcnt(2)\n\t"
            F16GZ("%[q0]", "64:67","96:99")
            "ds_read_b128 %[q0], %[aF] offset:192\n\t"
            "s_waitcnt lgkmcnt(2)\n\t"
            F16G("%[q1]", "68:71","100:103")
            "ds_read_b128 %[q1], %[aF] offset:256\n\t"
            "s_waitcnt lgkmcnt(2)\n\t"
            F16G("%[q2]", "72:75","104:107")
            "ds_read_b128 %[q2], %[aF] offset:320\n\t"
            "s_waitcnt lgkmcnt(2)\n\t"
            F16G("%[q0]", "76:79","108:111")
            "ds_read_b128 %[q0], %[aF] offset:384\n\t"
            "s_waitcnt lgkmcnt(2)\n\t"
            F16G("%[q1]", "80:83","112:115")
            "ds_read_b128 %[q1], %[aF] offset:448\n\t"
            "s_waitcnt lgkmcnt(2)\n\t"
            F16G("%[q2]", "84:87","116:119")
            "s_waitcnt lgkmcnt(1)\n\t"
            F16G("%[q0]", "88:91","120:123")
            "s_waitcnt lgkmcnt(0)\n\t"
            F16G("%[q1]", "92:95","124:127")
            "s_nop 7\n\ts_nop 7"
            : [aN0]"=&v"(aN0), [aN1]"=&v"(aN1),
              [q0]"=&v"(q0), [q1]"=&v"(q1), [q2]"=&v"(q2)
            : [aF]"v"(aF), [zq]"v"(zq)
            : ACLOB_N);
        __builtin_amdgcn_s_setprio(0);

        // gate math (exp2 form): aR/aZ rz matmul (x1/16), aN n matmul
        f16* hdF = hbufF[t & 1];
        uint8_t* hd8 = hbuf8[t & 1];
        const float C1N16 = -0.09016844005556021f;   // -log2e/16
#pragma unroll
        for (int tc = 0; tc < 2; tc++) {
            const int hcx = wid * 32 + tc * 16 + l16;
            const f32x4 vR = tc ? aR1 : aR0;
            const f32x4 vZ = tc ? aZ1 : aZ0;
            const f32x4 vN = tc ? aN1 : aN0;
#pragma unroll
            for (int rr = 0; rr < 4; rr++) {
                float rg = frcp(1.f + fexp2(fmaf(C1N16, vR[rr], (float)gcur[tc][rr])));
                float zg = frcp(1.f + fexp2(fmaf(C1N16, vZ[rr], (float)gcur[2 + tc][rr])));
                float t2 = fmaf(rg, fmaf(C2, vN[rr], bhn[tc]), (float)gcur[4 + tc][rr]);
                float e2 = fexp2(t2);
                float ng = fmaf(-2.f, frcp(e2 + 1.f), 1.f);   // tanh
                float h  = fmaf(zg, hm[tc][rr] - ng, ng);     // (1-z)n + z*h
                hm[tc][rr] = h;
                hdF[(quad * 4 + rr) * 280 + hcx] = (f16)h;
                int pk = __builtin_amdgcn_cvt_pk_fp8_f32(h, h, 0, false);
                hd8[(quad * 4 + rr) * 272 + hcx] = (uint8_t)pk;
            }
        }
        // prefetch gi for t+1 (registers; survives lgkm-only barrier)
        {
            int tn = (t < 30) ? t + 1 : 30;
            const f16* gsrc = gi + (size_t)tn * 98304 + lanebase;
#pragma unroll
            for (int u = 0; u < 6; u++)
                gcur[u] = *(const f16x4*)(gsrc + u * 2048);
        }
        BAR_LDS();
    }
    // output head: final h in hbufF[0]
    if (tid < 160) {
        int r = tid / 10, oc = tid - r * 10;
        const f16* hfin = hbufF[0];
        float s = b_out[oc];
        for (int k = 0; k < 256; k++) s += (float)hfin[r * 280 + k] * W_out[oc * 256 + k];
        out[(bb * 16 + r) * 10 + oc] = frcp(1.f + __expf(-s));
    }
}

// ---------------------------------------------------------------- launch
extern "C" void kernel_launch(void* const* d_in, const int* in_sizes, int n_in,
                              void* d_out, int out_size, void* d_ws, size_t ws_size,
                              hipStream_t stream) {
    const float* x     = (const float*)d_in[0];
    const float* W_aug = (const float*)d_in[1];
    // d_in[2] = b_aug — cancels in dx, unused
    const float* W_ih  = (const float*)d_in[3];
    const float* W_hh  = (const float*)d_in[4];
    const float* b_ih  = (const float*)d_in[5];
    const float* b_hh  = (const float*)d_in[6];
    const float* W_out = (const float*)d_in[7];
    const float* b_out = (const float*)d_in[8];
    float* out = (float*)d_out;

    char* ws = (char*)d_ws;
    const size_t SIG_BYTES  = (size_t)3968 * 2240 * 2;           // 17,776,640
    const size_t WIH_BYTES  = (size_t)768 * 2240 * 2;            //  3,440,640
    const size_t WHH_BYTES  = (size_t)768 * 256 * 2;             //    393,216
    const size_t WHH8_BYTES = (size_t)512 * 256;                 //    131,072
    const size_t GI_BYTES   = (size_t)31 * 8 * 6 * 512 * 4 * 2;  //  6,094,848
    if (ws_size < SIG_BYTES + WIH_BYTES + WHH_BYTES + WHH8_BYTES + GI_BYTES) return;
    f16* sig16    = (f16*)ws;
    f16* wih16    = (f16*)(ws + SIG_BYTES);
    f16* whh16    = (f16*)(ws + SIG_BYTES + WIH_BYTES);
    uint8_t* whh8 = (uint8_t*)(ws + SIG_BYTES + WIH_BYTES + WHH_BYTES);
    f16* giw      = (f16*)(ws + SIG_BYTES + WIH_BYTES + WHH_BYTES + WHH8_BYTES);

    hipLaunchKernelGGL(prep_kernel, dim3(2920), dim3(256), 0, stream,
                       x, W_aug, W_ih, W_hh, sig16, wih16, whh16, whh8);
    hipLaunchKernelGGL(gemm_kernel, dim3(744), dim3(512), 0, stream,
                       sig16, wih16, b_ih, b_hh, giw);
    hipLaunchKernelGGL(gru_kernel, dim3(8), dim3(512), 0, stream,
                       giw, whh16, whh8, b_hh, W_out, b_out, out);
}

// Round 14
// 177.257 us; speedup vs baseline: 1.1240x; 1.0482x over previous
//
#include <hip/hip_runtime.h>
#include <hip/hip_bf16.h>
#include <stdint.h>

// Problem constants
// B=128 STREAM=512 IN_CH=4 EXTRA=5 GROUPS=2 DEPTH=3 STEP=16 LENGTH=32 RNN=256 OUT=10
// C=10 SIG_C=1110 W=31 F=2220, padded K = 2240, GEMM M = 31*128 = 3968, N = 768
// gi layout (f16, COALESCED): chunk u of thread gtid at step (t,bb):
//   f16 offset = ((t*8+bb)*6 + u)*2048 + gtid*4,  u = gs*2+gtc in [0,6)
// gi VALUES pre-scaled for exp2-based gate math:
//   r,z chunks: -log2e*(gemm + b_ih + b_hh);  n chunks: 2*log2e*(gemm + b_ih)
// GEMM: in-block split-K (round-11 config, frozen).
// GRU (round 13 resubmit — round-13 bench was an infra failure, kernel never ran):
//   ALL THREE gates via v_mfma_f32_16x16x128_f8f6f4 (K=128). n gate reuses the
//   SAME fp8 h A-fragments (A0f/A1f) as rz -> removes the 8 ds_read_b128 f16
//   A-reads and 12 of 16 n MFMAs per thread per step. One 12-MFMA ILP block
//   (6 chains x 2-deep). h exchanged as fp8 only; hbufF written once (t=30)
//   for the output head. All W_hh rows in whh8 (x16, e4m3); n scale = C2/16.
// prep: whh8 covers all 768 rows (192KB).

typedef _Float16 f16;
typedef f16  f16x2 __attribute__((ext_vector_type(2)));
typedef f16  f16x4 __attribute__((ext_vector_type(4)));
typedef f16  f16x8 __attribute__((ext_vector_type(8)));
typedef float f32x2 __attribute__((ext_vector_type(2)));
typedef float f32x4 __attribute__((ext_vector_type(4)));
typedef float f32x8 __attribute__((ext_vector_type(8)));

#define ASYNC16(gp, lp) __builtin_amdgcn_global_load_lds( \
    (const __attribute__((address_space(1))) void*)(gp),  \
    (__attribute__((address_space(3))) void*)(lp), 16, 0, 0)

#define BAR_LDS() do { asm volatile("s_waitcnt lgkmcnt(0)" ::: "memory"); \
                       __builtin_amdgcn_s_barrier();                      \
                       asm volatile("" ::: "memory"); } while (0)

__device__ __forceinline__ float fexp2(float x) {
    float r; asm("v_exp_f32 %0, %1" : "=v"(r) : "v"(x)); return r;
}
__device__ __forceinline__ float frcp(float x) {
    float r; asm("v_rcp_f32 %0, %1" : "=v"(r) : "v"(x)); return r;
}

// ---------------------------------------------------------------- K0: prep
// blocks [0,840):    W_ih f32 -> f16 (pad 2220->2240), 8 elems/thread
// blocks [840,936):  W_hh f32 -> f16 (all) + fp8*16 (ALL rows), 8 elems/thread
// blocks [936,2920): signature chains, 4/block; LDS-staged coalesced row store
__global__ __launch_bounds__(256) void prep_kernel(const float* __restrict__ x,
                                                   const float* __restrict__ W_aug,
                                                   const float* __restrict__ Wih,
                                                   const float* __restrict__ Whh,
                                                   f16* __restrict__ sig16,
                                                   f16* __restrict__ wih16,
                                                   f16* __restrict__ whh16,
                                                   uint8_t* __restrict__ whh8) {
    __shared__ float dxs[4][31][10];
    __shared__ f16 srow[4][1112];                  // per-chain staging (1110 + pad)
    const int tid = threadIdx.x;
    if (blockIdx.x < 840) {
        int c = blockIdx.x * 256 + tid;          // chunk 0..215039
        int r = c / 280, kc = (c - r * 280) * 8;
        const float* src = Wih + (size_t)r * 2220 + kc;
        f16x8 o;
        if (kc + 8 <= 2220) {
            float4 v0 = *(const float4*)(src);
            float4 v1 = *(const float4*)(src + 4);
            o[0]=(f16)v0.x; o[1]=(f16)v0.y; o[2]=(f16)v0.z; o[3]=(f16)v0.w;
            o[4]=(f16)v1.x; o[5]=(f16)v1.y; o[6]=(f16)v1.z; o[7]=(f16)v1.w;
        } else {
#pragma unroll
            for (int j = 0; j < 8; j++)
                o[j] = (f16)((kc + j < 2220) ? src[j] : 0.0f);
        }
        *(f16x8*)(wih16 + (size_t)r * 2240 + kc) = o;
        return;
    }
    if (blockIdx.x < 936) {
        int c2 = ((int)blockIdx.x - 840) * 256 + tid;    // 0..24575
        int j8 = c2 * 8;
        float w[8];
        {
            float4 v0 = *(const float4*)(Whh + j8);
            float4 v1 = *(const float4*)(Whh + j8 + 4);
            w[0]=v0.x; w[1]=v0.y; w[2]=v0.z; w[3]=v0.w;
            w[4]=v1.x; w[5]=v1.y; w[6]=v1.z; w[7]=v1.w;
        }
        f16x8 o;
#pragma unroll
        for (int j = 0; j < 8; j++) o[j] = (f16)w[j];
        *(f16x8*)(whh16 + j8) = o;
        {                                        // ALL gate rows -> fp8 e4m3 (x16)
            uint32_t p01 = (uint32_t)__builtin_amdgcn_cvt_pk_fp8_f32(w[0]*16.f, w[1]*16.f, 0, false) & 0xffffu;
            uint32_t p23 = (uint32_t)__builtin_amdgcn_cvt_pk_fp8_f32(w[2]*16.f, w[3]*16.f, 0, false) & 0xffffu;
            uint32_t p45 = (uint32_t)__builtin_amdgcn_cvt_pk_fp8_f32(w[4]*16.f, w[5]*16.f, 0, false) & 0xffffu;
            uint32_t p67 = (uint32_t)__builtin_amdgcn_cvt_pk_fp8_f32(w[6]*16.f, w[7]*16.f, 0, false) & 0xffffu;
            uint2 st = make_uint2(p01 | (p23 << 16), p45 | (p67 << 16));
            *(uint2*)(whh8 + j8) = st;
        }
        return;
    }
    // ---- signature chains (block-uniform branch; __syncthreads safe)
    const int sub = tid >> 6, t64 = tid & 63;
    const int cid = ((int)blockIdx.x - 936) * 4 + sub;   // 0..7935
    const int w = cid % 31;
    const int bg = cid / 31;
    const int b = bg >> 1, g = bg & 1;
    if (t64 < 31) {
        int s = w * 16 + t64;
        const float4 x0 = *(const float4*)(x + ((size_t)b * 512 + s) * 4);
        const float4 x1 = *(const float4*)(x + ((size_t)b * 512 + s + 1) * 4);
        float d0 = x1.x - x0.x, d1 = x1.y - x0.y, d2 = x1.z - x0.z, d3 = x1.w - x0.w;
        dxs[sub][t64][0] = d0; dxs[sub][t64][1] = d1;
        dxs[sub][t64][2] = d2; dxs[sub][t64][3] = d3;
        dxs[sub][t64][4] = 1.0f / 511.0f;
#pragma unroll
        for (int e = 0; e < 5; e++) {
            const float* wa = W_aug + (g * 5 + e) * 4;
            dxs[sub][t64][5 + e] = d0 * wa[0] + d1 * wa[1] + d2 * wa[2] + d3 * wa[3];
        }
    }
    __syncthreads();
    size_t base = ((size_t)(w * 128 + b)) * 2240 + (size_t)g * 1110;
    if (t64 < 50) {
        int p0 = 2 * t64, p1 = p0 + 1;
        int i0 = p0 / 10, j0 = p0 % 10, j1 = j0 + 1;   // p0 even -> j1 <= 9
        const float* dz  = &dxs[sub][0][0];
        const float* pI  = dz + i0;
        const float* pJ0 = dz + j0;
        const float* pJ1 = dz + j1;
        float s3a[10], s3b[10];
#pragma unroll
        for (int k = 0; k < 10; k++) { s3a[k] = 0.f; s3b[k] = 0.f; }
        float s2a = 0.f, s2b = 0.f, s1 = 0.f;
        for (int l = 0; l < 31; l++) {
            const float* row = dz + l * 10;
            float di  = pI[l * 10];
            float dj0 = pJ0[l * 10];
            float dj1 = pJ1[l * 10];
            float t0 = s1 + di * (1.0f / 3.0f);
            float a0 = s2a + t0 * (0.5f * dj0);
            float a1 = s2b + t0 * (0.5f * dj1);
#pragma unroll
            for (int k = 0; k < 10; k++) {
                float dk = row[k];
                s3a[k] += a0 * dk;
                s3b[k] += a1 * dk;
            }
            float u = s1 + 0.5f * di;
            s2a += u * dj0;
            s2b += u * dj1;
            s1 += di;
        }
        *(f16x2*)&srow[sub][10 + p0] = (f16x2){(f16)s2a, (f16)s2b};
#pragma unroll
        for (int k = 0; k < 5; k++)
            *(f16x2*)&srow[sub][110 + p0 * 10 + 2 * k] =
                (f16x2){(f16)s3a[2 * k], (f16)s3a[2 * k + 1]};
#pragma unroll
        for (int k = 0; k < 5; k++)
            *(f16x2*)&srow[sub][110 + p1 * 10 + 2 * k] =
                (f16x2){(f16)s3b[2 * k], (f16)s3b[2 * k + 1]};
    } else if (t64 < 60) {
        int c = t64 - 50;
        const float* pc = &dxs[sub][0][0] + c;
        float s = 0.f;
        for (int l = 0; l < 31; l++) s += pc[l * 10];
        srow[sub][c] = (f16)s;
    }
    __syncthreads();
    for (int j = t64; j < 555; j += 64)
        *(f16x2*)(sig16 + base + 2 * j) = *(const f16x2*)&srow[sub][2 * j];
    if (g == 1 && t64 < 10)
        *(f16x2*)(sig16 + ((size_t)(w * 128 + b)) * 2240 + 2220 + 2 * t64) =
            (f16x2){(f16)0.0f, (f16)0.0f};
}

// ---------------------------------------------------------------- K2: gi = sig @ W_ih.T + biases (f16, coalesced GRU layout)
// 64x64 tile, 744 blocks x 512 thr; in-block split-K; LDS-scratch combine.
__global__ __launch_bounds__(512) void gemm_kernel(const f16* __restrict__ A,     // 3968 x 2240
                                                   const f16* __restrict__ Bw,    // 768 x 2240 f16
                                                   const float* __restrict__ bias,
                                                   const float* __restrict__ bhh,
                                                   f16* __restrict__ Cgi) {
    const int lin = blockIdx.x;          // 744 = 62 mb x 12 nc
    const int nc = lin % 12;
    const int mb = lin / 12;             // 0..61
    const int t = mb >> 1, half = mb & 1;
    __shared__ __align__(16) f16 As[2][3][64 * 32];   // 24 KB
    __shared__ __align__(16) f16 Bs[2][3][64 * 32];   // 24 KB
    __shared__ __align__(16) float sc[4][16 * 64];    // 16 KB (total 64 KB -> 2 blocks/CU)
    const int tid = threadIdx.x, lane = tid & 63, wid = tid >> 6;   // wid 0..7
    const int kh = wid >> 2, w4 = wid & 3;            // K-half, wave-in-half
    const int l16 = lane & 15, quad = lane >> 4;
    const int lrow = lane >> 2, lk = lane & 3;
    const int Nbase = nc * 64;
    const f16* gaA = A  + (size_t)(mb * 64 + w4 * 16 + lrow) * 2240 + kh * 1120 + lk * 8;
    const f16* gbB = Bw + (size_t)(Nbase + w4 * 16 + lrow) * 2240 + kh * 1120 + lk * 8;

#define GISSUE(KT, BUF) do { \
        int _k0 = (KT) * 32; \
        ASYNC16(gaA + _k0, &As[kh][BUF][(w4 * 16) * 32]); \
        ASYNC16(gbB + _k0, &Bs[kh][BUF][(w4 * 16) * 32]); } while (0)

#define GCOMPUTE(BUF) do { \
        f16x8 af, bf[4]; \
        af = *(const f16x8*)&As[kh][BUF][(w4 * 16 + l16) * 32 + quad * 8]; \
        _Pragma("unroll") \
        for (int nt = 0; nt < 4; nt++) \
            bf[nt] = *(const f16x8*)&Bs[kh][BUF][(nt * 16 + l16) * 32 + quad * 8]; \
        _Pragma("unroll") \
        for (int nt = 0; nt < 4; nt++) \
            acc[nt] = __builtin_amdgcn_mfma_f32_16x16x32_f16(af, bf[nt], acc[nt], 0, 0, 0); } while (0)

    f32x4 acc[4];
#pragma unroll
    for (int nt = 0; nt < 4; nt++) acc[nt] = (f32x4){0.f, 0.f, 0.f, 0.f};

    GISSUE(0, 0); GISSUE(1, 1);
    for (int kt = 0; kt < 33; kt++) {
        asm volatile("s_waitcnt vmcnt(2) lgkmcnt(0)\n\ts_barrier" ::: "memory");
        GISSUE(kt + 2, (kt + 2) % 3);
        GCOMPUTE(kt % 3);
    }
    asm volatile("s_waitcnt vmcnt(2) lgkmcnt(0)\n\ts_barrier" ::: "memory");
    GCOMPUTE(0);   // kt=33
    asm volatile("s_waitcnt vmcnt(0) lgkmcnt(0)\n\ts_barrier" ::: "memory");
    GCOMPUTE(1);   // kt=34

    // ---- combine K-halves via LDS scratch
    if (kh == 1) {
#pragma unroll
        for (int nt = 0; nt < 4; nt++)
#pragma unroll
            for (int rr = 0; rr < 4; rr++)
                sc[w4][(quad * 4 + rr) * 64 + nt * 16 + l16] = acc[nt][rr];
    }
    __syncthreads();
    if (kh == 0) {
        const float NEG_LOG2E = -1.4426950408889634f;
        const float TWO_LOG2E =  2.8853900817779268f;
        const int bbv = half * 4 + w4;
#pragma unroll
        for (int nt = 0; nt < 4; nt++) {
            int col = Nbase + nt * 16 + l16;
            float bvv = bias[col] + (col < 512 ? bhh[col] : 0.0f);   // fold b_hh into r,z
            float scl = (col < 512) ? NEG_LOG2E : TWO_LOG2E;
            int gs = col >> 8, hcc = col & 255;
            int gw = hcc >> 5, gtc = (hcc >> 4) & 1, gl = hcc & 15;
            int u = gs * 2 + gtc;
            int gtid = gw * 64 + quad * 16 + gl;
            size_t off = ((size_t)((t * 8 + bbv) * 6 + u)) * 2048 + (size_t)gtid * 4;
            f16x4 st;
#pragma unroll
            for (int rr = 0; rr < 4; rr++) {
                float v = acc[nt][rr] + sc[w4][(quad * 4 + rr) * 64 + nt * 16 + l16];
                st[rr] = (f16)((v + bvv) * scl);
            }
            *(f16x4*)(Cgi + off) = st;
        }
    }
#undef GISSUE
#undef GCOMPUTE
}

// ---------------------------------------------------------------- K3: GRU scan
// All gates K=128 fp8. Weights a[0:95]: rz a[0:63], n a[64:95].
#define ACLOB96 \
  "a0","a1","a2","a3","a4","a5","a6","a7","a8","a9","a10","a11","a12","a13","a14","a15", \
  "a16","a17","a18","a19","a20","a21","a22","a23","a24","a25","a26","a27","a28","a29","a30","a31", \
  "a32","a33","a34","a35","a36","a37","a38","a39","a40","a41","a42","a43","a44","a45","a46","a47", \
  "a48","a49","a50","a51","a52","a53","a54","a55","a56","a57","a58","a59","a60","a61","a62","a63", \
  "a64","a65","a66","a67","a68","a69","a70","a71","a72","a73","a74","a75","a76","a77","a78","a79", \
  "a80","a81","a82","a83","a84","a85","a86","a87","a88","a89","a90","a91","a92","a93","a94","a95"

// one K=128 fp8 weight fragment (16 gate cols x 128 k) -> 8 AGPRs
#define LF8X(A0,A1,A2,A3,A4,A5,A6,A7, G, TC, KF) do { \
  const uint8_t* _p = whh8 + (size_t)((G) * 256 + wid * 32 + (TC) * 16 + l16) * 256 + (KF) * 128 + quad * 32; \
  f32x4 _t0 = *(const f32x4*)_p; \
  f32x4 _t1 = *(const f32x4*)(_p + 16); \
  asm volatile("v_accvgpr_write_b32 a" #A0 ", %0\n\t" \
               "v_accvgpr_write_b32 a" #A1 ", %1\n\t" \
               "v_accvgpr_write_b32 a" #A2 ", %2\n\t" \
               "v_accvgpr_write_b32 a" #A3 ", %3\n\t" \
               "v_accvgpr_write_b32 a" #A4 ", %4\n\t" \
               "v_accvgpr_write_b32 a" #A5 ", %5\n\t" \
               "v_accvgpr_write_b32 a" #A6 ", %6\n\t" \
               "v_accvgpr_write_b32 a" #A7 ", %7" \
               :: "v"(_t0[0]), "v"(_t0[1]), "v"(_t0[2]), "v"(_t0[3]), \
                  "v"(_t1[0]), "v"(_t1[1]), "v"(_t1[2]), "v"(_t1[3]) \
               : "a" #A0, "a" #A1, "a" #A2, "a" #A3, \
                 "a" #A4, "a" #A5, "a" #A6, "a" #A7); } while (0)

__global__ __launch_bounds__(512, 2) void gru_kernel(const f16* __restrict__ gi,
                                                     const f16* __restrict__ whh16,
                                                     const uint8_t* __restrict__ whh8,
                                                     const float* __restrict__ b_hh,
                                                     const float* __restrict__ W_out,
                                                     const float* __restrict__ b_out,
                                                     float* __restrict__ out) {
    __shared__ __align__(16) f16 hbufF[16 * 280];         // final h only (head)
    __shared__ __align__(16) uint8_t hbuf8[2][16 * 272];  // fp8 h (all gates A)
    const int tid = threadIdx.x, lane = tid & 63, wid = tid >> 6;   // wid 0..7
    const int quad = lane >> 4, l16 = lane & 15;
    const int bb = blockIdx.x;

    for (int i = tid; i < 16 * 272; i += 512) hbuf8[1][i] = 0;

    // weights: (g, tc, kf) -> rz a[((g*2+tc)*2+kf)*8), n a[64 + (tc*2+kf)*8)
    LF8X(0,1,2,3,4,5,6,7,         0,0,0);
    LF8X(8,9,10,11,12,13,14,15,   0,0,1);
    LF8X(16,17,18,19,20,21,22,23, 0,1,0);
    LF8X(24,25,26,27,28,29,30,31, 0,1,1);
    LF8X(32,33,34,35,36,37,38,39, 1,0,0);
    LF8X(40,41,42,43,44,45,46,47, 1,0,1);
    LF8X(48,49,50,51,52,53,54,55, 1,1,0);
    LF8X(56,57,58,59,60,61,62,63, 1,1,1);
    LF8X(64,65,66,67,68,69,70,71, 2,0,0);
    LF8X(72,73,74,75,76,77,78,79, 2,0,1);
    LF8X(80,81,82,83,84,85,86,87, 2,1,0);
    LF8X(88,89,90,91,92,93,94,95, 2,1,1);

    const float C2 = 2.8853900817779268f;   // 2*log2e
    float bhn[2];
#pragma unroll
    for (int tc = 0; tc < 2; tc++) bhn[tc] = C2 * b_hh[512 + wid * 32 + tc * 16 + l16];
    float hm[2][4];
#pragma unroll
    for (int tc = 0; tc < 2; tc++)
#pragma unroll
        for (int rr = 0; rr < 4; rr++) hm[tc][rr] = 0.f;

    // coalesced gi: per (t,bb) slab = 12288 f16; chunk u at u*2048; thread at tid*4
    const size_t lanebase = (size_t)bb * 12288 + (size_t)tid * 4;
    f16x4 gcur[6];
#pragma unroll
    for (int u = 0; u < 6; u++)
        gcur[u] = *(const f16x4*)(gi + lanebase + u * 2048);

    const f32x4 zq = (f32x4){0.f, 0.f, 0.f, 0.f};

    BAR_LDS();

    for (int t = 0; t < 31; t++) {
        const uint8_t* hb = ((t & 1) ? hbuf8[0] : hbuf8[1]) + (size_t)l16 * 272 + quad * 32;
        f32x4 aR0, aR1, aZ0, aZ1, aN0, aN1;
        // A-fragments: 32B/lane per K=128 frag (kf=0 at +0, kf=1 at +128)
        f32x4 u0 = *(const f32x4*)(hb);
        f32x4 u1 = *(const f32x4*)(hb + 16);
        f32x4 u2 = *(const f32x4*)(hb + 128);
        f32x4 u3 = *(const f32x4*)(hb + 144);
        f32x8 A0f, A1f;
        A0f[0]=u0[0]; A0f[1]=u0[1]; A0f[2]=u0[2]; A0f[3]=u0[3];
        A0f[4]=u1[0]; A0f[5]=u1[1]; A0f[6]=u1[2]; A0f[7]=u1[3];
        A1f[0]=u2[0]; A1f[1]=u2[1]; A1f[2]=u2[2]; A1f[3]=u2[3];
        A1f[4]=u3[0]; A1f[5]=u3[1]; A1f[6]=u3[2]; A1f[7]=u3[3];
        __builtin_amdgcn_s_setprio(1);
        asm volatile(   // all gates: 12 x K=128 fp8 MFMA (6 chains x 2-deep)
            "v_mfma_f32_16x16x128_f8f6f4 %[r0], %[A0], a[0:7],   %[zq]\n\t"
            "v_mfma_f32_16x16x128_f8f6f4 %[r1], %[A0], a[16:23], %[zq]\n\t"
            "v_mfma_f32_16x16x128_f8f6f4 %[z0], %[A0], a[32:39], %[zq]\n\t"
            "v_mfma_f32_16x16x128_f8f6f4 %[z1], %[A0], a[48:55], %[zq]\n\t"
            "v_mfma_f32_16x16x128_f8f6f4 %[n0], %[A0], a[64:71], %[zq]\n\t"
            "v_mfma_f32_16x16x128_f8f6f4 %[n1], %[A0], a[80:87], %[zq]\n\t"
            "v_mfma_f32_16x16x128_f8f6f4 %[r0], %[A1], a[8:15],  %[r0]\n\t"
            "v_mfma_f32_16x16x128_f8f6f4 %[r1], %[A1], a[24:31], %[r1]\n\t"
            "v_mfma_f32_16x16x128_f8f6f4 %[z0], %[A1], a[40:47], %[z0]\n\t"
            "v_mfma_f32_16x16x128_f8f6f4 %[z1], %[A1], a[56:63], %[z1]\n\t"
            "v_mfma_f32_16x16x128_f8f6f4 %[n0], %[A1], a[72:79], %[n0]\n\t"
            "v_mfma_f32_16x16x128_f8f6f4 %[n1], %[A1], a[88:95], %[n1]\n\t"
            "s_nop 7\n\ts_nop 7"
            : [r0]"=&v"(aR0), [r1]"=&v"(aR1), [z0]"=&v"(aZ0), [z1]"=&v"(aZ1),
              [n0]"=&v"(aN0), [n1]"=&v"(aN1)
            : [A0]"v"(A0f), [A1]"v"(A1f), [zq]"v"(zq)
            : ACLOB96);
        __builtin_amdgcn_s_setprio(0);

        // gate math (exp2 form): all matmuls carry x16 weight scale
        uint8_t* hd8 = hbuf8[t & 1];
        const float C1N16 = -0.09016844005556021f;   // -log2e/16
        const float C2_16 =  0.18033688011112042f;   //  2*log2e/16
#pragma unroll
        for (int tc = 0; tc < 2; tc++) {
            const int hcx = wid * 32 + tc * 16 + l16;
            const f32x4 vR = tc ? aR1 : aR0;
            const f32x4 vZ = tc ? aZ1 : aZ0;
            const f32x4 vN = tc ? aN1 : aN0;
#pragma unroll
            for (int rr = 0; rr < 4; rr++) {
                float rg = frcp(1.f + fexp2(fmaf(C1N16, vR[rr], (float)gcur[tc][rr])));
                float zg = frcp(1.f + fexp2(fmaf(C1N16, vZ[rr], (float)gcur[2 + tc][rr])));
                float t2 = fmaf(rg, fmaf(C2_16, vN[rr], bhn[tc]), (float)gcur[4 + tc][rr]);
                float e2 = fexp2(t2);
                float ng = fmaf(-2.f, frcp(e2 + 1.f), 1.f);   // tanh
                float h  = fmaf(zg, hm[tc][rr] - ng, ng);     // (1-z)n + z*h
                hm[tc][rr] = h;
                int pk = __builtin_amdgcn_cvt_pk_fp8_f32(h, h, 0, false);
                hd8[(quad * 4 + rr) * 272 + hcx] = (uint8_t)pk;
                if (t == 30)
                    hbufF[(quad * 4 + rr) * 280 + hcx] = (f16)h;
            }
        }
        // prefetch gi for t+1 (registers; survives lgkm-only barrier)
        {
            int tn = (t < 30) ? t + 1 : 30;
            const f16* gsrc = gi + (size_t)tn * 98304 + lanebase;
#pragma unroll
            for (int u = 0; u < 6; u++)
                gcur[u] = *(const f16x4*)(gsrc + u * 2048);
        }
        BAR_LDS();
    }
    // output head: final h in hbufF
    if (tid < 160) {
        int r = tid / 10, oc = tid - r * 10;
        const f16* hfin = hbufF;
        float s = b_out[oc];
        for (int k = 0; k < 256; k++) s += (float)hfin[r * 280 + k] * W_out[oc * 256 + k];
        out[(bb * 16 + r) * 10 + oc] = frcp(1.f + __expf(-s));
    }
}

// ---------------------------------------------------------------- launch
extern "C" void kernel_launch(void* const* d_in, const int* in_sizes, int n_in,
                              void* d_out, int out_size, void* d_ws, size_t ws_size,
                              hipStream_t stream) {
    const float* x     = (const float*)d_in[0];
    const float* W_aug = (const float*)d_in[1];
    // d_in[2] = b_aug — cancels in dx, unused
    const float* W_ih  = (const float*)d_in[3];
    const float* W_hh  = (const float*)d_in[4];
    const float* b_ih  = (const float*)d_in[5];
    const float* b_hh  = (const float*)d_in[6];
    const float* W_out = (const float*)d_in[7];
    const float* b_out = (const float*)d_in[8];
    float* out = (float*)d_out;

    char* ws = (char*)d_ws;
    const size_t SIG_BYTES  = (size_t)3968 * 2240 * 2;           // 17,776,640
    const size_t WIH_BYTES  = (size_t)768 * 2240 * 2;            //  3,440,640
    const size_t WHH_BYTES  = (size_t)768 * 256 * 2;             //    393,216
    const size_t WHH8_BYTES = (size_t)768 * 256;                 //    196,608
    const size_t GI_BYTES   = (size_t)31 * 8 * 6 * 512 * 4 * 2;  //  6,094,848
    if (ws_size < SIG_BYTES + WIH_BYTES + WHH_BYTES + WHH8_BYTES + GI_BYTES) return;
    f16* sig16    = (f16*)ws;
    f16* wih16    = (f16*)(ws + SIG_BYTES);
    f16* whh16    = (f16*)(ws + SIG_BYTES + WIH_BYTES);
    uint8_t* whh8 = (uint8_t*)(ws + SIG_BYTES + WIH_BYTES + WHH_BYTES);
    f16* giw      = (f16*)(ws + SIG_BYTES + WIH_BYTES + WHH_BYTES + WHH8_BYTES);

    hipLaunchKernelGGL(prep_kernel, dim3(2920), dim3(256), 0, stream,
                       x, W_aug, W_ih, W_hh, sig16, wih16, whh16, whh8);
    hipLaunchKernelGGL(gemm_kernel, dim3(744), dim3(512), 0, stream,
                       sig16, wih16, b_ih, b_hh, giw);
    hipLaunchKernelGGL(gru_kernel, dim3(8), dim3(512), 0, stream,
                       giw, whh16, whh8, b_hh, W_out, b_out, out);
}

// Round 15
// 176.378 us; speedup vs baseline: 1.1296x; 1.0050x over previous
//
#include <hip/hip_runtime.h>
#include <hip/hip_bf16.h>
#include <stdint.h>

// Problem constants
// B=128 STREAM=512 IN_CH=4 EXTRA=5 GROUPS=2 DEPTH=3 STEP=16 LENGTH=32 RNN=256 OUT=10
// C=10 SIG_C=1110 W=31 F=2220, padded K = 2240, GEMM M = 31*128 = 3968, N = 768
// gi layout (f16, COALESCED): chunk u of thread gtid at step (t,bb):
//   f16 offset = ((t*8+bb)*6 + u)*2048 + gtid*4,  u = gs*2+gtc in [0,6)
// gi VALUES pre-scaled for exp2-based gate math:
//   r,z chunks: -log2e*(gemm + b_ih + b_hh);  n chunks: 2*log2e*(gemm + b_ih)
// GEMM: in-block split-K (round-11 config, frozen).
// GRU (round 15): 16 waves (1024 thr, 4 waves/SIMD). Round-14 counters: 55%
//   issue-busy, 45% idle at 2 waves/SIMD -> TLP-addressable now that the step
//   body is lean (round-10's 16-wave fail was the heavy f16/LDS-pipeline body).
//   Wave w owns col-frag w (16 cols) x ALL 3 gates: 6 K=128 fp8 MFMA/wave
//   (3 indep 2-deep chains), 4-elem gate math, 4 byte-stores. AGPR pin 48/wave
//   -> ~90 unspillable < 128 (fits 4 waves/EU, unlike round 1/10). Same
//   fragments + summation order -> bitwise-identical output.
// prep: unchanged (all W_hh rows fp8 x16 in whh8).

typedef _Float16 f16;
typedef f16  f16x2 __attribute__((ext_vector_type(2)));
typedef f16  f16x4 __attribute__((ext_vector_type(4)));
typedef f16  f16x8 __attribute__((ext_vector_type(8)));
typedef float f32x2 __attribute__((ext_vector_type(2)));
typedef float f32x4 __attribute__((ext_vector_type(4)));
typedef float f32x8 __attribute__((ext_vector_type(8)));

#define ASYNC16(gp, lp) __builtin_amdgcn_global_load_lds( \
    (const __attribute__((address_space(1))) void*)(gp),  \
    (__attribute__((address_space(3))) void*)(lp), 16, 0, 0)

#define BAR_LDS() do { asm volatile("s_waitcnt lgkmcnt(0)" ::: "memory"); \
                       __builtin_amdgcn_s_barrier();                      \
                       asm volatile("" ::: "memory"); } while (0)

__device__ __forceinline__ float fexp2(float x) {
    float r; asm("v_exp_f32 %0, %1" : "=v"(r) : "v"(x)); return r;
}
__device__ __forceinline__ float frcp(float x) {
    float r; asm("v_rcp_f32 %0, %1" : "=v"(r) : "v"(x)); return r;
}

// ---------------------------------------------------------------- K0: prep
// blocks [0,840):    W_ih f32 -> f16 (pad 2220->2240), 8 elems/thread
// blocks [840,936):  W_hh f32 -> f16 (all) + fp8*16 (ALL rows), 8 elems/thread
// blocks [936,2920): signature chains, 4/block; LDS-staged coalesced row store
__global__ __launch_bounds__(256) void prep_kernel(const float* __restrict__ x,
                                                   const float* __restrict__ W_aug,
                                                   const float* __restrict__ Wih,
                                                   const float* __restrict__ Whh,
                                                   f16* __restrict__ sig16,
                                                   f16* __restrict__ wih16,
                                                   f16* __restrict__ whh16,
                                                   uint8_t* __restrict__ whh8) {
    __shared__ float dxs[4][31][10];
    __shared__ f16 srow[4][1112];                  // per-chain staging (1110 + pad)
    const int tid = threadIdx.x;
    if (blockIdx.x < 840) {
        int c = blockIdx.x * 256 + tid;          // chunk 0..215039
        int r = c / 280, kc = (c - r * 280) * 8;
        const float* src = Wih + (size_t)r * 2220 + kc;
        f16x8 o;
        if (kc + 8 <= 2220) {
            float4 v0 = *(const float4*)(src);
            float4 v1 = *(const float4*)(src + 4);
            o[0]=(f16)v0.x; o[1]=(f16)v0.y; o[2]=(f16)v0.z; o[3]=(f16)v0.w;
            o[4]=(f16)v1.x; o[5]=(f16)v1.y; o[6]=(f16)v1.z; o[7]=(f16)v1.w;
        } else {
#pragma unroll
            for (int j = 0; j < 8; j++)
                o[j] = (f16)((kc + j < 2220) ? src[j] : 0.0f);
        }
        *(f16x8*)(wih16 + (size_t)r * 2240 + kc) = o;
        return;
    }
    if (blockIdx.x < 936) {
        int c2 = ((int)blockIdx.x - 840) * 256 + tid;    // 0..24575
        int j8 = c2 * 8;
        float w[8];
        {
            float4 v0 = *(const float4*)(Whh + j8);
            float4 v1 = *(const float4*)(Whh + j8 + 4);
            w[0]=v0.x; w[1]=v0.y; w[2]=v0.z; w[3]=v0.w;
            w[4]=v1.x; w[5]=v1.y; w[6]=v1.z; w[7]=v1.w;
        }
        f16x8 o;
#pragma unroll
        for (int j = 0; j < 8; j++) o[j] = (f16)w[j];
        *(f16x8*)(whh16 + j8) = o;
        {                                        // ALL gate rows -> fp8 e4m3 (x16)
            uint32_t p01 = (uint32_t)__builtin_amdgcn_cvt_pk_fp8_f32(w[0]*16.f, w[1]*16.f, 0, false) & 0xffffu;
            uint32_t p23 = (uint32_t)__builtin_amdgcn_cvt_pk_fp8_f32(w[2]*16.f, w[3]*16.f, 0, false) & 0xffffu;
            uint32_t p45 = (uint32_t)__builtin_amdgcn_cvt_pk_fp8_f32(w[4]*16.f, w[5]*16.f, 0, false) & 0xffffu;
            uint32_t p67 = (uint32_t)__builtin_amdgcn_cvt_pk_fp8_f32(w[6]*16.f, w[7]*16.f, 0, false) & 0xffffu;
            uint2 st = make_uint2(p01 | (p23 << 16), p45 | (p67 << 16));
            *(uint2*)(whh8 + j8) = st;
        }
        return;
    }
    // ---- signature chains (block-uniform branch; __syncthreads safe)
    const int sub = tid >> 6, t64 = tid & 63;
    const int cid = ((int)blockIdx.x - 936) * 4 + sub;   // 0..7935
    const int w = cid % 31;
    const int bg = cid / 31;
    const int b = bg >> 1, g = bg & 1;
    if (t64 < 31) {
        int s = w * 16 + t64;
        const float4 x0 = *(const float4*)(x + ((size_t)b * 512 + s) * 4);
        const float4 x1 = *(const float4*)(x + ((size_t)b * 512 + s + 1) * 4);
        float d0 = x1.x - x0.x, d1 = x1.y - x0.y, d2 = x1.z - x0.z, d3 = x1.w - x0.w;
        dxs[sub][t64][0] = d0; dxs[sub][t64][1] = d1;
        dxs[sub][t64][2] = d2; dxs[sub][t64][3] = d3;
        dxs[sub][t64][4] = 1.0f / 511.0f;
#pragma unroll
        for (int e = 0; e < 5; e++) {
            const float* wa = W_aug + (g * 5 + e) * 4;
            dxs[sub][t64][5 + e] = d0 * wa[0] + d1 * wa[1] + d2 * wa[2] + d3 * wa[3];
        }
    }
    __syncthreads();
    size_t base = ((size_t)(w * 128 + b)) * 2240 + (size_t)g * 1110;
    if (t64 < 50) {
        int p0 = 2 * t64, p1 = p0 + 1;
        int i0 = p0 / 10, j0 = p0 % 10, j1 = j0 + 1;   // p0 even -> j1 <= 9
        const float* dz  = &dxs[sub][0][0];
        const float* pI  = dz + i0;
        const float* pJ0 = dz + j0;
        const float* pJ1 = dz + j1;
        float s3a[10], s3b[10];
#pragma unroll
        for (int k = 0; k < 10; k++) { s3a[k] = 0.f; s3b[k] = 0.f; }
        float s2a = 0.f, s2b = 0.f, s1 = 0.f;
        for (int l = 0; l < 31; l++) {
            const float* row = dz + l * 10;
            float di  = pI[l * 10];
            float dj0 = pJ0[l * 10];
            float dj1 = pJ1[l * 10];
            float t0 = s1 + di * (1.0f / 3.0f);
            float a0 = s2a + t0 * (0.5f * dj0);
            float a1 = s2b + t0 * (0.5f * dj1);
#pragma unroll
            for (int k = 0; k < 10; k++) {
                float dk = row[k];
                s3a[k] += a0 * dk;
                s3b[k] += a1 * dk;
            }
            float u = s1 + 0.5f * di;
            s2a += u * dj0;
            s2b += u * dj1;
            s1 += di;
        }
        *(f16x2*)&srow[sub][10 + p0] = (f16x2){(f16)s2a, (f16)s2b};
#pragma unroll
        for (int k = 0; k < 5; k++)
            *(f16x2*)&srow[sub][110 + p0 * 10 + 2 * k] =
                (f16x2){(f16)s3a[2 * k], (f16)s3a[2 * k + 1]};
#pragma unroll
        for (int k = 0; k < 5; k++)
            *(f16x2*)&srow[sub][110 + p1 * 10 + 2 * k] =
                (f16x2){(f16)s3b[2 * k], (f16)s3b[2 * k + 1]};
    } else if (t64 < 60) {
        int c = t64 - 50;
        const float* pc = &dxs[sub][0][0] + c;
        float s = 0.f;
        for (int l = 0; l < 31; l++) s += pc[l * 10];
        srow[sub][c] = (f16)s;
    }
    __syncthreads();
    for (int j = t64; j < 555; j += 64)
        *(f16x2*)(sig16 + base + 2 * j) = *(const f16x2*)&srow[sub][2 * j];
    if (g == 1 && t64 < 10)
        *(f16x2*)(sig16 + ((size_t)(w * 128 + b)) * 2240 + 2220 + 2 * t64) =
            (f16x2){(f16)0.0f, (f16)0.0f};
}

// ---------------------------------------------------------------- K2: gi = sig @ W_ih.T + biases (f16, coalesced GRU layout)
// 64x64 tile, 744 blocks x 512 thr; in-block split-K; LDS-scratch combine.
__global__ __launch_bounds__(512) void gemm_kernel(const f16* __restrict__ A,     // 3968 x 2240
                                                   const f16* __restrict__ Bw,    // 768 x 2240 f16
                                                   const float* __restrict__ bias,
                                                   const float* __restrict__ bhh,
                                                   f16* __restrict__ Cgi) {
    const int lin = blockIdx.x;          // 744 = 62 mb x 12 nc
    const int nc = lin % 12;
    const int mb = lin / 12;             // 0..61
    const int t = mb >> 1, half = mb & 1;
    __shared__ __align__(16) f16 As[2][3][64 * 32];   // 24 KB
    __shared__ __align__(16) f16 Bs[2][3][64 * 32];   // 24 KB
    __shared__ __align__(16) float sc[4][16 * 64];    // 16 KB (total 64 KB -> 2 blocks/CU)
    const int tid = threadIdx.x, lane = tid & 63, wid = tid >> 6;   // wid 0..7
    const int kh = wid >> 2, w4 = wid & 3;            // K-half, wave-in-half
    const int l16 = lane & 15, quad = lane >> 4;
    const int lrow = lane >> 2, lk = lane & 3;
    const int Nbase = nc * 64;
    const f16* gaA = A  + (size_t)(mb * 64 + w4 * 16 + lrow) * 2240 + kh * 1120 + lk * 8;
    const f16* gbB = Bw + (size_t)(Nbase + w4 * 16 + lrow) * 2240 + kh * 1120 + lk * 8;

#define GISSUE(KT, BUF) do { \
        int _k0 = (KT) * 32; \
        ASYNC16(gaA + _k0, &As[kh][BUF][(w4 * 16) * 32]); \
        ASYNC16(gbB + _k0, &Bs[kh][BUF][(w4 * 16) * 32]); } while (0)

#define GCOMPUTE(BUF) do { \
        f16x8 af, bf[4]; \
        af = *(const f16x8*)&As[kh][BUF][(w4 * 16 + l16) * 32 + quad * 8]; \
        _Pragma("unroll") \
        for (int nt = 0; nt < 4; nt++) \
            bf[nt] = *(const f16x8*)&Bs[kh][BUF][(nt * 16 + l16) * 32 + quad * 8]; \
        _Pragma("unroll") \
        for (int nt = 0; nt < 4; nt++) \
            acc[nt] = __builtin_amdgcn_mfma_f32_16x16x32_f16(af, bf[nt], acc[nt], 0, 0, 0); } while (0)

    f32x4 acc[4];
#pragma unroll
    for (int nt = 0; nt < 4; nt++) acc[nt] = (f32x4){0.f, 0.f, 0.f, 0.f};

    GISSUE(0, 0); GISSUE(1, 1);
    for (int kt = 0; kt < 33; kt++) {
        asm volatile("s_waitcnt vmcnt(2) lgkmcnt(0)\n\ts_barrier" ::: "memory");
        GISSUE(kt + 2, (kt + 2) % 3);
        GCOMPUTE(kt % 3);
    }
    asm volatile("s_waitcnt vmcnt(2) lgkmcnt(0)\n\ts_barrier" ::: "memory");
    GCOMPUTE(0);   // kt=33
    asm volatile("s_waitcnt vmcnt(0) lgkmcnt(0)\n\ts_barrier" ::: "memory");
    GCOMPUTE(1);   // kt=34

    // ---- combine K-halves via LDS scratch
    if (kh == 1) {
#pragma unroll
        for (int nt = 0; nt < 4; nt++)
#pragma unroll
            for (int rr = 0; rr < 4; rr++)
                sc[w4][(quad * 4 + rr) * 64 + nt * 16 + l16] = acc[nt][rr];
    }
    __syncthreads();
    if (kh == 0) {
        const float NEG_LOG2E = -1.4426950408889634f;
        const float TWO_LOG2E =  2.8853900817779268f;
        const int bbv = half * 4 + w4;
#pragma unroll
        for (int nt = 0; nt < 4; nt++) {
            int col = Nbase + nt * 16 + l16;
            float bvv = bias[col] + (col < 512 ? bhh[col] : 0.0f);   // fold b_hh into r,z
            float scl = (col < 512) ? NEG_LOG2E : TWO_LOG2E;
            int gs = col >> 8, hcc = col & 255;
            int gw = hcc >> 5, gtc = (hcc >> 4) & 1, gl = hcc & 15;
            int u = gs * 2 + gtc;
            int gtid = gw * 64 + quad * 16 + gl;
            size_t off = ((size_t)((t * 8 + bbv) * 6 + u)) * 2048 + (size_t)gtid * 4;
            f16x4 st;
#pragma unroll
            for (int rr = 0; rr < 4; rr++) {
                float v = acc[nt][rr] + sc[w4][(quad * 4 + rr) * 64 + nt * 16 + l16];
                st[rr] = (f16)((v + bvv) * scl);
            }
            *(f16x4*)(Cgi + off) = st;
        }
    }
#undef GISSUE
#undef GCOMPUTE
}

// ---------------------------------------------------------------- K3: GRU scan (16 waves)
// All gates K=128 fp8; wave w owns col-frag w x {r,z,n}. Weights a[0:47].
#define ACLOB48 \
  "a0","a1","a2","a3","a4","a5","a6","a7","a8","a9","a10","a11","a12","a13","a14","a15", \
  "a16","a17","a18","a19","a20","a21","a22","a23","a24","a25","a26","a27","a28","a29","a30","a31", \
  "a32","a33","a34","a35","a36","a37","a38","a39","a40","a41","a42","a43","a44","a45","a46","a47"

// one K=128 fp8 weight fragment (16 gate cols x 128 k) -> 8 AGPRs
#define LF8X(A0,A1,A2,A3,A4,A5,A6,A7, G, KF) do { \
  const uint8_t* _p = whh8 + (size_t)((G) * 256 + wid * 16 + l16) * 256 + (KF) * 128 + quad * 32; \
  f32x4 _t0 = *(const f32x4*)_p; \
  f32x4 _t1 = *(const f32x4*)(_p + 16); \
  asm volatile("v_accvgpr_write_b32 a" #A0 ", %0\n\t" \
               "v_accvgpr_write_b32 a" #A1 ", %1\n\t" \
               "v_accvgpr_write_b32 a" #A2 ", %2\n\t" \
               "v_accvgpr_write_b32 a" #A3 ", %3\n\t" \
               "v_accvgpr_write_b32 a" #A4 ", %4\n\t" \
               "v_accvgpr_write_b32 a" #A5 ", %5\n\t" \
               "v_accvgpr_write_b32 a" #A6 ", %6\n\t" \
               "v_accvgpr_write_b32 a" #A7 ", %7" \
               :: "v"(_t0[0]), "v"(_t0[1]), "v"(_t0[2]), "v"(_t0[3]), \
                  "v"(_t1[0]), "v"(_t1[1]), "v"(_t1[2]), "v"(_t1[3]) \
               : "a" #A0, "a" #A1, "a" #A2, "a" #A3, \
                 "a" #A4, "a" #A5, "a" #A6, "a" #A7); } while (0)

__global__ __launch_bounds__(1024, 4) void gru_kernel(const f16* __restrict__ gi,
                                                      const f16* __restrict__ whh16,
                                                      const uint8_t* __restrict__ whh8,
                                                      const float* __restrict__ b_hh,
                                                      const float* __restrict__ W_out,
                                                      const float* __restrict__ b_out,
                                                      float* __restrict__ out) {
    __shared__ __align__(16) f16 hbufF[16 * 280];         // final h only (head)
    __shared__ __align__(16) uint8_t hbuf8[2][16 * 272];  // fp8 h (all gates A)
    const int tid = threadIdx.x, lane = tid & 63, wid = tid >> 6;   // wid 0..15
    const int quad = lane >> 4, l16 = lane & 15;
    const int bb = blockIdx.x;

    for (int i = tid; i < 16 * 272; i += 1024) hbuf8[1][i] = 0;

    // weights: (G gate, KF k-frag) -> a[(G*2+KF)*8 .. +8)
    LF8X(0,1,2,3,4,5,6,7,         0, 0);
    LF8X(8,9,10,11,12,13,14,15,   0, 1);
    LF8X(16,17,18,19,20,21,22,23, 1, 0);
    LF8X(24,25,26,27,28,29,30,31, 1, 1);
    LF8X(32,33,34,35,36,37,38,39, 2, 0);
    LF8X(40,41,42,43,44,45,46,47, 2, 1);

    const float C2 = 2.8853900817779268f;   // 2*log2e
    const int hcx = wid * 16 + l16;         // owned gate column
    const float bhn = C2 * b_hh[512 + hcx];
    float hm[4];
#pragma unroll
    for (int rr = 0; rr < 4; rr++) hm[rr] = 0.f;

    // coalesced gi: wave owns cols wid*16..+16 -> u-chunk parity wid&1,
    // thread slot (wid>>1)*64 + quad*16 + l16; gate chunks at +gs*4096.
    const size_t lanebase = (size_t)bb * 12288 + (size_t)(wid & 1) * 2048
                          + (size_t)((wid >> 1) * 64 + quad * 16 + l16) * 4;
    f16x4 gcur[3];
#pragma unroll
    for (int gs = 0; gs < 3; gs++)
        gcur[gs] = *(const f16x4*)(gi + lanebase + (size_t)gs * 4096);

    const f32x4 zq = (f32x4){0.f, 0.f, 0.f, 0.f};

    BAR_LDS();

    for (int t = 0; t < 31; t++) {
        const uint8_t* hb = ((t & 1) ? hbuf8[0] : hbuf8[1]) + (size_t)l16 * 272 + quad * 32;
        f32x4 aR, aZ, aN;
        // A-fragments: 32B/lane per K=128 frag (kf=0 at +0, kf=1 at +128)
        f32x4 u0 = *(const f32x4*)(hb);
        f32x4 u1 = *(const f32x4*)(hb + 16);
        f32x4 u2 = *(const f32x4*)(hb + 128);
        f32x4 u3 = *(const f32x4*)(hb + 144);
        f32x8 A0f, A1f;
        A0f[0]=u0[0]; A0f[1]=u0[1]; A0f[2]=u0[2]; A0f[3]=u0[3];
        A0f[4]=u1[0]; A0f[5]=u1[1]; A0f[6]=u1[2]; A0f[7]=u1[3];
        A1f[0]=u2[0]; A1f[1]=u2[1]; A1f[2]=u2[2]; A1f[3]=u2[3];
        A1f[4]=u3[0]; A1f[5]=u3[1]; A1f[6]=u3[2]; A1f[7]=u3[3];
        __builtin_amdgcn_s_setprio(1);
        asm volatile(   // 6 x K=128 fp8 MFMA (3 independent chains x 2-deep)
            "v_mfma_f32_16x16x128_f8f6f4 %[r], %[A0], a[0:7],   %[zq]\n\t"
            "v_mfma_f32_16x16x128_f8f6f4 %[z], %[A0], a[16:23], %[zq]\n\t"
            "v_mfma_f32_16x16x128_f8f6f4 %[n], %[A0], a[32:39], %[zq]\n\t"
            "v_mfma_f32_16x16x128_f8f6f4 %[r], %[A1], a[8:15],  %[r]\n\t"
            "v_mfma_f32_16x16x128_f8f6f4 %[z], %[A1], a[24:31], %[z]\n\t"
            "v_mfma_f32_16x16x128_f8f6f4 %[n], %[A1], a[40:47], %[n]\n\t"
            "s_nop 7\n\ts_nop 7"
            : [r]"=&v"(aR), [z]"=&v"(aZ), [n]"=&v"(aN)
            : [A0]"v"(A0f), [A1]"v"(A1f), [zq]"v"(zq)
            : ACLOB48);
        __builtin_amdgcn_s_setprio(0);

        // gate math (exp2 form): all matmuls carry x16 weight scale
        uint8_t* hd8 = hbuf8[t & 1];
        const float C1N16 = -0.09016844005556021f;   // -log2e/16
        const float C2_16 =  0.18033688011112042f;   //  2*log2e/16
#pragma unroll
        for (int rr = 0; rr < 4; rr++) {
            float rg = frcp(1.f + fexp2(fmaf(C1N16, aR[rr], (float)gcur[0][rr])));
            float zg = frcp(1.f + fexp2(fmaf(C1N16, aZ[rr], (float)gcur[1][rr])));
            float t2 = fmaf(rg, fmaf(C2_16, aN[rr], bhn), (float)gcur[2][rr]);
            float e2 = fexp2(t2);
            float ng = fmaf(-2.f, frcp(e2 + 1.f), 1.f);   // tanh
            float h  = fmaf(zg, hm[rr] - ng, ng);         // (1-z)n + z*h
            hm[rr] = h;
            int pk = __builtin_amdgcn_cvt_pk_fp8_f32(h, h, 0, false);
            hd8[(quad * 4 + rr) * 272 + hcx] = (uint8_t)pk;
            if (t == 30)
                hbufF[(quad * 4 + rr) * 280 + hcx] = (f16)h;
        }
        // prefetch gi for t+1 (registers; survives lgkm-only barrier)
        {
            int tn = (t < 30) ? t + 1 : 30;
            const f16* gsrc = gi + (size_t)tn * 98304 + lanebase;
#pragma unroll
            for (int gs = 0; gs < 3; gs++)
                gcur[gs] = *(const f16x4*)(gsrc + (size_t)gs * 4096);
        }
        BAR_LDS();
    }
    // output head: final h in hbufF
    if (tid < 160) {
        int r = tid / 10, oc = tid - r * 10;
        const f16* hfin = hbufF;
        float s = b_out[oc];
        for (int k = 0; k < 256; k++) s += (float)hfin[r * 280 + k] * W_out[oc * 256 + k];
        out[(bb * 16 + r) * 10 + oc] = frcp(1.f + __expf(-s));
    }
}

// ---------------------------------------------------------------- launch
extern "C" void kernel_launch(void* const* d_in, const int* in_sizes, int n_in,
                              void* d_out, int out_size, void* d_ws, size_t ws_size,
                              hipStream_t stream) {
    const float* x     = (const float*)d_in[0];
    const float* W_aug = (const float*)d_in[1];
    // d_in[2] = b_aug — cancels in dx, unused
    const float* W_ih  = (const float*)d_in[3];
    const float* W_hh  = (const float*)d_in[4];
    const float* b_ih  = (const float*)d_in[5];
    const float* b_hh  = (const float*)d_in[6];
    const float* W_out = (const float*)d_in[7];
    const float* b_out = (const float*)d_in[8];
    float* out = (float*)d_out;

    char* ws = (char*)d_ws;
    const size_t SIG_BYTES  = (size_t)3968 * 2240 * 2;           // 17,776,640
    const size_t WIH_BYTES  = (size_t)768 * 2240 * 2;            //  3,440,640
    const size_t WHH_BYTES  = (size_t)768 * 256 * 2;             //    393,216
    const size_t WHH8_BYTES = (size_t)768 * 256;                 //    196,608
    const size_t GI_BYTES   = (size_t)31 * 8 * 6 * 512 * 4 * 2;  //  6,094,848
    if (ws_size < SIG_BYTES + WIH_BYTES + WHH_BYTES + WHH8_BYTES + GI_BYTES) return;
    f16* sig16    = (f16*)ws;
    f16* wih16    = (f16*)(ws + SIG_BYTES);
    f16* whh16    = (f16*)(ws + SIG_BYTES + WIH_BYTES);
    uint8_t* whh8 = (uint8_t*)(ws + SIG_BYTES + WIH_BYTES + WHH_BYTES);
    f16* giw      = (f16*)(ws + SIG_BYTES + WIH_BYTES + WHH_BYTES + WHH8_BYTES);

    hipLaunchKernelGGL(prep_kernel, dim3(2920), dim3(256), 0, stream,
                       x, W_aug, W_ih, W_hh, sig16, wih16, whh16, whh8);
    hipLaunchKernelGGL(gemm_kernel, dim3(744), dim3(512), 0, stream,
                       sig16, wih16, b_ih, b_hh, giw);
    hipLaunchKernelGGL(gru_kernel, dim3(8), dim3(1024), 0, stream,
                       giw, whh16, whh8, b_hh, W_out, b_out, out);
}